// Round 14
// baseline (376.813 us; speedup 1.0000x reference)
//
#include <hip/hip_runtime.h>

#define NV 50000
#define NE 10000
#define NH 512
#define NI_TOT 300000
#define PB 40000
#define NT_A 391   // ceil(NV/128) row tiles for tiled A

typedef __attribute__((ext_vector_type(8))) short short8v;    // 8 bf16
typedef __attribute__((ext_vector_type(4))) float f32x4;
typedef __attribute__((ext_vector_type(4))) unsigned short ushort4v;

__device__ __forceinline__ unsigned short f2bf(float x) {
    union { float f; unsigned int u; } v; v.f = x;
    unsigned int r = (v.u + 0x7FFFu + ((v.u >> 16) & 1u)) >> 16;   // RNE
    return (unsigned short)r;
}
__device__ __forceinline__ unsigned int pack2bf(float lo, float hi) {
    return (unsigned int)f2bf(lo) | ((unsigned int)f2bf(hi) << 16);
}
__device__ __forceinline__ float bf2f(unsigned short u) {
    union { unsigned int x; float f; } v; v.x = ((unsigned int)u) << 16;
    return v.f;
}
__device__ __forceinline__ void gload16(const void* g, void* l) {
    __builtin_amdgcn_global_load_lds(
        (const __attribute__((address_space(1))) unsigned int*)g,
        (__attribute__((address_space(3))) unsigned int*)l, 16, 0, 0);
}

// ---------------- cast v -> tiled+swizzled bf16 A (zero-padded tail rows) -------
__global__ __launch_bounds__(256) void cast_tile_swz(
    const float* __restrict__ src, unsigned short* __restrict__ dst,
    int M, int ngroups)
{
    const int i = blockIdx.x * 256 + threadIdx.x;
    if (i >= ngroups) return;
    const int r  = i >> 6;
    const int gq = i & 63;
    uint4 o = make_uint4(0u, 0u, 0u, 0u);
    if (r < M) {
        const float4 a = *reinterpret_cast<const float4*>(&src[(size_t)r * NH + gq * 8]);
        const float4 b = *reinterpret_cast<const float4*>(&src[(size_t)r * NH + gq * 8 + 4]);
        o.x = pack2bf(a.x, a.y); o.y = pack2bf(a.z, a.w);
        o.z = pack2bf(b.x, b.y); o.w = pack2bf(b.z, b.w);
    }
    const size_t base = ((size_t)(r >> 7) * 8 + (gq >> 3)) * 16384;
    const int phys = (((r & 127) * 128 + (gq & 7) * 16)) ^ ((r & 7) << 4);
    *reinterpret_cast<uint4*>((char*)dst + base + phys) = o;
}

// ---------------- W -> tiled+swizzled bf16 Bt (for GEMM1) ----------------
__global__ __launch_bounds__(256) void transpose_cast_w_tiled(
    const float* __restrict__ W, unsigned short* __restrict__ Wt)
{
    __shared__ float t[32][33];
    const int bx = blockIdx.x;          // n tile
    const int by = blockIdx.y;          // k tile
    const int tx = threadIdx.x & 31;
    const int ty = threadIdx.x >> 5;
    #pragma unroll
    for (int j = 0; j < 32; j += 8)
        t[ty + j][tx] = W[(size_t)(by * 32 + ty + j) * NH + bx * 32 + tx];
    __syncthreads();
    #pragma unroll
    for (int j = 0; j < 32; j += 8) {
        const int n = bx * 32 + ty + j;
        const int k = by * 32 + tx;
        const size_t base = ((size_t)(n >> 7) * 8 + (k >> 6)) * 16384;
        const int phys = (((n & 127) * 128 + (k & 63) * 2)) ^ ((n & 7) << 4);
        *reinterpret_cast<unsigned short*>((char*)Wt + base + phys) = f2bf(t[tx][ty + j]);
    }
}

// ---------------- W -> plain transposed bf16 (for GEMM2) ----------------
__global__ __launch_bounds__(256) void transpose_cast_w(
    const float* __restrict__ W, unsigned short* __restrict__ Wt)
{
    __shared__ float t[32][33];
    const int bx = blockIdx.x;
    const int by = blockIdx.y;
    const int tx = threadIdx.x & 31;
    const int ty = threadIdx.x >> 5;
    #pragma unroll
    for (int j = 0; j < 32; j += 8)
        t[ty + j][tx] = W[(size_t)(by * 32 + ty + j) * NH + bx * 32 + tx];
    __syncthreads();
    #pragma unroll
    for (int j = 0; j < 32; j += 8)
        Wt[(size_t)(bx * 32 + ty + j) * NH + by * 32 + tx] = f2bf(t[tx][ty + j]);
}

// ---------------- GEMM1: tiled-swizzled A/B via global_load_lds, bf16 out -------
__global__ __launch_bounds__(256) void gemm_mfma_gld(
    const unsigned short* __restrict__ At, const unsigned short* __restrict__ Btl,
    const float* __restrict__ bias, const float* __restrict__ rowscale,
    unsigned short* __restrict__ Cbf, int M)
{
    __shared__ __align__(16) unsigned char As[16384];
    __shared__ __align__(16) unsigned char Bs[16384];

    const int tid  = threadIdx.x;
    const int lane = tid & 63;
    const int wave = tid >> 6;
    const int wm   = (wave & 1) * 64;
    const int wn   = (wave >> 1) * 64;
    const int tileM = blockIdx.y * 128;
    const int col0  = blockIdx.x * 128;

    const char* Abase = (const char*)At  + (size_t)blockIdx.y * 8 * 16384;
    const char* Bbase = (const char*)Btl + (size_t)blockIdx.x * 8 * 16384;

    f32x4 acc[4][4] = {};

    for (int s = 0; s < 8; ++s) {
        const char* ga = Abase + s * 16384 + (size_t)wave * 4096 + lane * 16;
        const char* gb = Bbase + s * 16384 + (size_t)wave * 4096 + lane * 16;
        char* la = (char*)As + wave * 4096;
        char* lb = (char*)Bs + wave * 4096;
        #pragma unroll
        for (int i = 0; i < 4; ++i) {
            gload16(ga + i * 1024, la + i * 1024);
            gload16(gb + i * 1024, lb + i * 1024);
        }
        __syncthreads();   // drains vmcnt for global_load_lds

        #pragma unroll
        for (int ks = 0; ks < 2; ++ks) {
            const int kb = ks * 64 + (lane >> 4) * 16;
            short8v af[4], bfr[4];
            #pragma unroll
            for (int mf = 0; mf < 4; ++mf) {
                const int r = wm + mf * 16 + (lane & 15);
                af[mf] = *reinterpret_cast<const short8v*>(
                    (const char*)As + ((r * 128 + kb) ^ ((r & 7) << 4)));
            }
            #pragma unroll
            for (int nf = 0; nf < 4; ++nf) {
                const int n = wn + nf * 16 + (lane & 15);
                bfr[nf] = *reinterpret_cast<const short8v*>(
                    (const char*)Bs + ((n * 128 + kb) ^ ((n & 7) << 4)));
            }
            #pragma unroll
            for (int mf = 0; mf < 4; ++mf)
                #pragma unroll
                for (int nf = 0; nf < 4; ++nf)
                    acc[mf][nf] = __builtin_amdgcn_mfma_f32_16x16x32_bf16(
                        af[mf], bfr[nf], acc[mf][nf], 0, 0, 0);
        }
        __syncthreads();
    }

    const int rgrp = (lane >> 4) * 4;
    const int cin  = lane & 15;
    #pragma unroll
    for (int mf = 0; mf < 4; ++mf) {
        #pragma unroll
        for (int r = 0; r < 4; ++r) {
            const int row = tileM + wm + mf * 16 + rgrp + r;
            if (row < M) {
                const float rs = rowscale[row];
                #pragma unroll
                for (int nf = 0; nf < 4; ++nf) {
                    const int col = col0 + wn + nf * 16 + cin;
                    Cbf[(size_t)row * NH + col] =
                        f2bf(fmaxf(acc[mf][nf][r] + bias[col], 0.f) * rs);
                }
            }
        }
    }
}

// ---------------- GEMM2: row-major bf16 A, plain Bt, reg staging ----------------
__global__ __launch_bounds__(256) void gemm_mfma_bf16a_bf16out(
    const unsigned short* __restrict__ Abf, const unsigned short* __restrict__ Bt,
    const float* __restrict__ bias, const float* __restrict__ rowscale,
    unsigned short* __restrict__ Cbf, int M)
{
    __shared__ unsigned short As[128][72];
    __shared__ unsigned short Bs[128][72];

    const int tid  = threadIdx.x;
    const int lane = tid & 63;
    const int wave = tid >> 6;
    const int wm   = (wave & 1) * 64;
    const int wn   = (wave >> 1) * 64;
    const int tileM = blockIdx.y * 128;
    const int col0  = blockIdx.x * 128;

    f32x4 acc[4][4] = {};
    const short8v zero8 = {0, 0, 0, 0, 0, 0, 0, 0};

    for (int k0 = 0; k0 < NH; k0 += 64) {
        #pragma unroll
        for (int j = 0; j < 4; ++j) {
            const int chunk = j * 256 + tid;
            const int n  = chunk >> 3;
            const int kc = (chunk & 7) * 8;
            const int arow = tileM + n;
            short8v a = zero8;
            if (arow < M)
                a = *reinterpret_cast<const short8v*>(&Abf[(size_t)arow * NH + k0 + kc]);
            *reinterpret_cast<short8v*>(&As[n][kc]) = a;
        }
        #pragma unroll
        for (int j = 0; j < 4; ++j) {
            const int chunk = j * 256 + tid;
            const int n  = chunk >> 3;
            const int kc = (chunk & 7) * 8;
            short8v b = *reinterpret_cast<const short8v*>(
                &Bt[(size_t)(col0 + n) * NH + k0 + kc]);
            *reinterpret_cast<short8v*>(&Bs[n][kc]) = b;
        }
        __syncthreads();

        #pragma unroll
        for (int ks = 0; ks < 2; ++ks) {
            const int koff = ks * 32 + (lane >> 4) * 8;
            short8v af[4], bfr[4];
            #pragma unroll
            for (int mf = 0; mf < 4; ++mf)
                af[mf] = *reinterpret_cast<short8v*>(&As[wm + mf * 16 + (lane & 15)][koff]);
            #pragma unroll
            for (int nf = 0; nf < 4; ++nf)
                bfr[nf] = *reinterpret_cast<short8v*>(&Bs[wn + nf * 16 + (lane & 15)][koff]);
            #pragma unroll
            for (int mf = 0; mf < 4; ++mf)
                #pragma unroll
                for (int nf = 0; nf < 4; ++nf)
                    acc[mf][nf] = __builtin_amdgcn_mfma_f32_16x16x32_bf16(
                        af[mf], bfr[nf], acc[mf][nf], 0, 0, 0);
        }
        __syncthreads();
    }

    const int rgrp = (lane >> 4) * 4;
    const int cin  = lane & 15;
    #pragma unroll
    for (int mf = 0; mf < 4; ++mf) {
        #pragma unroll
        for (int r = 0; r < 4; ++r) {
            const int row = tileM + wm + mf * 16 + rgrp + r;
            if (row < M) {
                const float rs = rowscale[row];
                #pragma unroll
                for (int nf = 0; nf < 4; ++nf) {
                    const int col = col0 + wn + nf * 16 + cin;
                    Cbf[(size_t)row * NH + col] =
                        f2bf(fmaxf(acc[mf][nf][r] + bias[col], 0.f) * rs);
                }
            }
        }
    }
}

// ---------------- f32 GEMM (fallback) ----------------
__global__ __launch_bounds__(256) void gemm_relu_scale(
    const float* __restrict__ A, const float* __restrict__ B,
    const float* __restrict__ bias, const float* __restrict__ rowscale,
    float* __restrict__ C, int M)
{
    __shared__ float As[16][68];
    __shared__ float Bs[16][64];
    const int tid = threadIdx.x;
    const int tx = tid & 15;
    const int ty = tid >> 4;
    const int tileM = blockIdx.y * 64;
    const int col0  = blockIdx.x * 64;
    const int lr  = tid >> 2;
    const int lk4 = (tid & 3) * 4;
    const int bc  = tid & 63;
    const int bk  = tid >> 6;
    float acc[4][4] = {};
    for (int k0 = 0; k0 < NH; k0 += 16) {
        const int arow = tileM + lr;
        float4 av = make_float4(0.f, 0.f, 0.f, 0.f);
        if (arow < M)
            av = *reinterpret_cast<const float4*>(&A[(size_t)arow * NH + k0 + lk4]);
        As[lk4 + 0][lr] = av.x; As[lk4 + 1][lr] = av.y;
        As[lk4 + 2][lr] = av.z; As[lk4 + 3][lr] = av.w;
        #pragma unroll
        for (int jj = 0; jj < 4; ++jj) {
            const int kk = bk + jj * 4;
            Bs[kk][bc] = B[(size_t)(k0 + kk) * NH + col0 + bc];
        }
        __syncthreads();
        #pragma unroll
        for (int kk = 0; kk < 16; ++kk) {
            float4 a = *reinterpret_cast<const float4*>(&As[kk][ty * 4]);
            float4 b = *reinterpret_cast<const float4*>(&Bs[kk][tx * 4]);
            acc[0][0] += a.x * b.x; acc[0][1] += a.x * b.y; acc[0][2] += a.x * b.z; acc[0][3] += a.x * b.w;
            acc[1][0] += a.y * b.x; acc[1][1] += a.y * b.y; acc[1][2] += a.y * b.z; acc[1][3] += a.y * b.w;
            acc[2][0] += a.z * b.x; acc[2][1] += a.z * b.y; acc[2][2] += a.z * b.z; acc[2][3] += a.z * b.w;
            acc[3][0] += a.w * b.x; acc[3][1] += a.w * b.y; acc[3][2] += a.w * b.z; acc[3][3] += a.w * b.w;
        }
        __syncthreads();
    }
    const int rbase = tileM + ty * 4;
    const int cbase = col0 + tx * 4;
    #pragma unroll
    for (int i = 0; i < 4; ++i) {
        const int row = rbase + i;
        if (row < M) {
            const float s = rowscale[row];
            float4 o;
            o.x = fmaxf(acc[i][0] + bias[cbase + 0], 0.f) * s;
            o.y = fmaxf(acc[i][1] + bias[cbase + 1], 0.f) * s;
            o.z = fmaxf(acc[i][2] + bias[cbase + 2], 0.f) * s;
            o.w = fmaxf(acc[i][3] + bias[cbase + 3], 0.f) * s;
            *reinterpret_cast<float4*>(&C[(size_t)row * NH + cbase]) = o;
        }
    }
}

// ---------------- CSR build ----------------
__global__ __launch_bounds__(256) void zero_ints(int* __restrict__ p, int n)
{
    const int i = blockIdx.x * 256 + threadIdx.x;
    if (i < n) p[i] = 0;
}

__global__ __launch_bounds__(256) void hist_kernel(
    const int* __restrict__ gi, const int* __restrict__ pi,
    int* __restrict__ e_cnt, int* __restrict__ v_cnt)
{
    const int i = blockIdx.x * 256 + threadIdx.x;
    if (i >= NI_TOT) return;
    atomicAdd(&e_cnt[gi[i]], 1);
    atomicAdd(&v_cnt[pi[i]], 1);
}

__global__ __launch_bounds__(256) void scan_local(
    const int* __restrict__ cnt, int* __restrict__ off, int* __restrict__ bsum, int n)
{
    __shared__ int buf[256];
    const int t = threadIdx.x;
    const int gi = blockIdx.x * 256 + t;
    int x = (gi < n) ? cnt[gi] : 0;
    buf[t] = x;
    __syncthreads();
    #pragma unroll
    for (int d = 1; d < 256; d <<= 1) {
        int y = (t >= d) ? buf[t - d] : 0;
        __syncthreads();
        buf[t] += y;
        __syncthreads();
    }
    if (gi < n) off[gi + 1] = buf[t];
    if (t == 255) bsum[blockIdx.x] = buf[255];
}

__global__ __launch_bounds__(256) void scan_bsums(int* __restrict__ bsum, int nb)
{
    __shared__ int buf[256];
    const int t = threadIdx.x;
    const int x = (t < nb) ? bsum[t] : 0;
    buf[t] = x;
    __syncthreads();
    #pragma unroll
    for (int d = 1; d < 256; d <<= 1) {
        int y = (t >= d) ? buf[t - d] : 0;
        __syncthreads();
        buf[t] += y;
        __syncthreads();
    }
    if (t < nb) bsum[t] = buf[t] - x;
}

__global__ __launch_bounds__(256) void scan_add(
    int* __restrict__ off, const int* __restrict__ bsum, int n)
{
    const int gi = blockIdx.x * 256 + threadIdx.x;
    if (gi == 0) off[0] = 0;
    if (gi < n) off[gi + 1] += bsum[blockIdx.x];
}

__global__ __launch_bounds__(256) void scan_kernel(
    const int* __restrict__ cnt, int* __restrict__ off, int n)
{
    __shared__ int buf[256];
    __shared__ int carry_s;
    const int t = threadIdx.x;
    if (t == 0) { off[0] = 0; carry_s = 0; }
    __syncthreads();
    for (int base = 0; base < n; base += 256) {
        int x = (base + t < n) ? cnt[base + t] : 0;
        buf[t] = x;
        __syncthreads();
        #pragma unroll
        for (int d = 1; d < 256; d <<= 1) {
            int y = (t >= d) ? buf[t - d] : 0;
            __syncthreads();
            buf[t] += y;
            __syncthreads();
        }
        if (base + t < n) off[base + t + 1] = buf[t] + carry_s;
        __syncthreads();
        if (t == 255) carry_s += buf[255];
        __syncthreads();
    }
}

__global__ __launch_bounds__(256) void fill_kernel(
    const int* __restrict__ gi, const int* __restrict__ pi,
    const int* __restrict__ e_off, int* __restrict__ e_cur, int* __restrict__ e_list,
    const int* __restrict__ v_off, int* __restrict__ v_cur, int* __restrict__ v_list)
{
    const int i = blockIdx.x * 256 + threadIdx.x;
    if (i >= NI_TOT) return;
    const int g = gi[i];
    e_list[e_off[g] + atomicAdd(&e_cur[g], 1)] = i;
    const int p = pi[i];
    v_list[v_off[p] + atomicAdd(&v_cur[p], 1)] = i;
}

// ---------------- bf16-gather aggregation ----------------
__global__ __launch_bounds__(128) void agg_e_bf16(
    const float* __restrict__ e, const unsigned short* __restrict__ ve_bf,
    const int* __restrict__ player_idx, const float* __restrict__ v_reg_weight,
    const int* __restrict__ e_off, const int* __restrict__ e_list,
    const float* __restrict__ e_reg_sum, float* __restrict__ out_e,
    unsigned short* __restrict__ Ebf)
{
    __shared__ int   sp[128];
    __shared__ float sw[128];
    const int g = blockIdx.x;
    const int t = threadIdx.x;
    const int c = t << 2;
    f32x4 acc = __builtin_nontemporal_load(
        reinterpret_cast<const f32x4*>(&e[(size_t)g * NH + c]));
    const int beg = e_off[g], end = e_off[g + 1];
    for (int base = beg; base < end; base += 128) {
        const int m = min(128, end - base);
        __syncthreads();
        if (t < m) {
            const int i = e_list[base + t];
            sp[t] = player_idx[i];
            sw[t] = v_reg_weight[i];
        }
        __syncthreads();
        #pragma unroll 4
        for (int j = 0; j < m; ++j) {
            const int   p = sp[j];
            const float w = sw[j];
            ushort4v x = *reinterpret_cast<const ushort4v*>(&ve_bf[(size_t)p * NH + c]);
            acc.x += w * bf2f(x.x); acc.y += w * bf2f(x.y);
            acc.z += w * bf2f(x.z); acc.w += w * bf2f(x.w);
        }
    }
    const float inv = 1.0f / e_reg_sum[g];
    acc.x *= inv; acc.y *= inv; acc.z *= inv; acc.w *= inv;
    __builtin_nontemporal_store(acc,
        reinterpret_cast<f32x4*>(&out_e[(size_t)g * NH + c]));
    uint2 pk;
    pk.x = pack2bf(acc.x, acc.y);
    pk.y = pack2bf(acc.z, acc.w);
    *reinterpret_cast<uint2*>(&Ebf[(size_t)g * NH + c]) = pk;    // cached: GEMM2 re-reads
}

// XCD-column-split agg_v: block b -> vertex b>>2, column quarter b&3.
// With round-robin bid%8 -> XCD, each XCD gathers only 1/4 of ev_bf (2.56 MB < 4 MiB L2).
__global__ __launch_bounds__(128) void agg_v_bf16_q(
    const float* __restrict__ v, const float* __restrict__ v_weight,
    const unsigned short* __restrict__ ev_bf,
    const int* __restrict__ game_idx, const float* __restrict__ e_reg_weight,
    const int* __restrict__ v_off, const int* __restrict__ v_list,
    const float* __restrict__ v_reg_sum, float* __restrict__ out_v)
{
    __shared__ int   sg[128];
    __shared__ float sw[128];
    const int b = blockIdx.x;
    const int p = b >> 2;
    const int q = b & 3;
    const int t = threadIdx.x;
    const int c = q * 128 + t;          // one f32 column per thread
    const float vw = v_weight[p];
    float acc = __builtin_nontemporal_load(&v[(size_t)p * NH + c]) * vw;
    const int beg = v_off[p], end = v_off[p + 1];
    for (int base = beg; base < end; base += 128) {
        const int m = min(128, end - base);
        __syncthreads();
        if (t < m) {
            const int i = v_list[base + t];
            sg[t] = game_idx[i];
            sw[t] = e_reg_weight[i];
        }
        __syncthreads();
        #pragma unroll 4
        for (int j = 0; j < m; ++j) {
            acc += sw[j] * bf2f(ev_bf[(size_t)sg[j] * NH + c]);
        }
    }
    acc *= 1.0f / v_reg_sum[p];
    __builtin_nontemporal_store(acc, &out_v[(size_t)p * NH + c]);
}

// ---------------- f32-gather aggregation (fallback) ----------------
__global__ __launch_bounds__(128) void agg_e_kernel(
    const float* __restrict__ e, const float* __restrict__ ve_w,
    const int* __restrict__ player_idx, const float* __restrict__ v_reg_weight,
    const int* __restrict__ e_off, const int* __restrict__ e_list,
    const float* __restrict__ e_reg_sum, float* __restrict__ out_e)
{
    __shared__ int   sp[128];
    __shared__ float sw[128];
    const int g = blockIdx.x;
    const int t = threadIdx.x;
    const int c = t << 2;
    float4 acc = *reinterpret_cast<const float4*>(&e[(size_t)g * NH + c]);
    const int beg = e_off[g], end = e_off[g + 1];
    for (int base = beg; base < end; base += 128) {
        const int m = min(128, end - base);
        __syncthreads();
        if (t < m) {
            const int i = e_list[base + t];
            sp[t] = player_idx[i];
            sw[t] = v_reg_weight[i];
        }
        __syncthreads();
        #pragma unroll 4
        for (int j = 0; j < m; ++j) {
            const int   p = sp[j];
            const float w = sw[j];
            float4 x = *reinterpret_cast<const float4*>(&ve_w[(size_t)p * NH + c]);
            acc.x += w * x.x; acc.y += w * x.y; acc.z += w * x.z; acc.w += w * x.w;
        }
    }
    const float inv = 1.0f / e_reg_sum[g];
    acc.x *= inv; acc.y *= inv; acc.z *= inv; acc.w *= inv;
    *reinterpret_cast<float4*>(&out_e[(size_t)g * NH + c]) = acc;
}

__global__ __launch_bounds__(128) void agg_v_kernel(
    const float* __restrict__ v, const float* __restrict__ v_weight,
    const float* __restrict__ ev_w,
    const int* __restrict__ game_idx, const float* __restrict__ e_reg_weight,
    const int* __restrict__ v_off, const int* __restrict__ v_list,
    const float* __restrict__ v_reg_sum, float* __restrict__ out_v)
{
    __shared__ int   sg[128];
    __shared__ float sw[128];
    const int p = blockIdx.x;
    const int t = threadIdx.x;
    const int c = t << 2;
    const float vw = v_weight[p];
    float4 acc = *reinterpret_cast<const float4*>(&v[(size_t)p * NH + c]);
    acc.x *= vw; acc.y *= vw; acc.z *= vw; acc.w *= vw;
    const int beg = v_off[p], end = v_off[p + 1];
    for (int base = beg; base < end; base += 128) {
        const int m = min(128, end - base);
        __syncthreads();
        if (t < m) {
            const int i = v_list[base + t];
            sg[t] = game_idx[i];
            sw[t] = e_reg_weight[i];
        }
        __syncthreads();
        #pragma unroll 4
        for (int j = 0; j < m; ++j) {
            const int   g = sg[j];
            const float w = sw[j];
            float4 x = *reinterpret_cast<const float4*>(&ev_w[(size_t)g * NH + c]);
            acc.x += w * x.x; acc.y += w * x.y; acc.z += w * x.z; acc.w += w * x.w;
        }
    }
    const float inv = 1.0f / v_reg_sum[p];
    acc.x *= inv; acc.y *= inv; acc.z *= inv; acc.w *= inv;
    *reinterpret_cast<float4*>(&out_v[(size_t)p * NH + c]) = acc;
}

// ---------------- atomic-path fallback kernels ----------------
__global__ __launch_bounds__(256) void scatter_add_kernel(
    const float* __restrict__ src, const int* __restrict__ gidx,
    const int* __restrict__ sidx, const float* __restrict__ regw,
    float* __restrict__ dst, int ni, int smin, int smax, int gmax)
{
    const int i = blockIdx.x * 2 + (threadIdx.x >> 7);
    if (i >= ni) return;
    const int s = sidx[i];
    if (s < smin || s >= smax) return;
    const int g = gidx[i];
    if (g < 0 || g >= gmax) return;
    const int c = (threadIdx.x & 127) << 2;
    const float w = regw[i];
    float4 val = *reinterpret_cast<const float4*>(&src[(size_t)g * NH + c]);
    float* d = &dst[(size_t)s * NH + c];
    atomicAdd(d + 0, val.x * w);
    atomicAdd(d + 1, val.y * w);
    atomicAdd(d + 2, val.z * w);
    atomicAdd(d + 3, val.w * w);
}

__global__ __launch_bounds__(256) void recompute_ev_scatter(
    const float* __restrict__ e_out, const float* __restrict__ W,
    const float* __restrict__ bias, const float* __restrict__ e_weight,
    const int* __restrict__ player_idx, const int* __restrict__ game_idx,
    const float* __restrict__ e_reg_weight, float* __restrict__ out_v, int pmin)
{
    const int i = blockIdx.x;
    const int p = player_idx[i];
    if (p < pmin || p >= NV) return;
    const int g = game_idx[i];
    if (g < 0 || g >= NE) return;
    __shared__ float eg[NH];
    const int t = threadIdx.x;
    eg[t]       = e_out[(size_t)g * NH + t];
    eg[t + 256] = e_out[(size_t)g * NH + t + 256];
    __syncthreads();
    float s0 = 0.f, s1 = 0.f;
    #pragma unroll 4
    for (int k = 0; k < NH; ++k) {
        const float ek = eg[k];
        s0 += ek * W[(size_t)k * NH + t];
        s1 += ek * W[(size_t)k * NH + t + 256];
    }
    const float ew = e_weight[g] * e_reg_weight[i];
    atomicAdd(&out_v[(size_t)p * NH + t],       fmaxf(s0 + bias[t], 0.f) * ew);
    atomicAdd(&out_v[(size_t)p * NH + t + 256], fmaxf(s1 + bias[t + 256], 0.f) * ew);
}

__global__ __launch_bounds__(256) void init_copy(
    const float* __restrict__ src, float* __restrict__ dst, int n4)
{
    const int i = blockIdx.x * 256 + threadIdx.x;
    if (i < n4)
        reinterpret_cast<float4*>(dst)[i] = reinterpret_cast<const float4*>(src)[i];
}

__global__ __launch_bounds__(256) void init_scale_rows(
    const float* __restrict__ src, const float* __restrict__ w,
    float* __restrict__ dst, int n4)
{
    const int i = blockIdx.x * 256 + threadIdx.x;
    if (i >= n4) return;
    const int row = i >> 7;
    const float s = w[row];
    float4 v = reinterpret_cast<const float4*>(src)[i];
    v.x *= s; v.y *= s; v.z *= s; v.w *= s;
    reinterpret_cast<float4*>(dst)[i] = v;
}

__global__ __launch_bounds__(256) void div_rows(
    const float* __restrict__ rs, float* __restrict__ x, int n4)
{
    const int i = blockIdx.x * 256 + threadIdx.x;
    if (i >= n4) return;
    const int row = i >> 7;
    const float inv = 1.0f / rs[row];
    float4 v = reinterpret_cast<float4*>(x)[i];
    v.x *= inv; v.y *= inv; v.z *= inv; v.w *= inv;
    reinterpret_cast<float4*>(x)[i] = v;
}

extern "C" void kernel_launch(void* const* d_in, const int* in_sizes, int n_in,
                              void* d_out, int out_size, void* d_ws, size_t ws_size,
                              hipStream_t stream) {
    const float* v            = (const float*)d_in[0];
    const float* e            = (const float*)d_in[1];
    const int*   player_idx   = (const int*)d_in[2];
    const int*   game_idx     = (const int*)d_in[3];
    const float* W_v2e        = (const float*)d_in[5];
    const float* W_e2v        = (const float*)d_in[6];
    const float* b_v          = (const float*)d_in[7];
    const float* b_e          = (const float*)d_in[8];

    const float* a9  = (const float*)d_in[9];
    const float* a10 = (const float*)d_in[10];
    const float* v_weight = (in_sizes[9]  == NV) ? a9  : a10;
    const float* e_weight = (in_sizes[9]  == NV) ? a10 : a9;
    const float* v_reg_weight = (const float*)d_in[11];
    const float* e_reg_weight = (const float*)d_in[12];
    const float* a13 = (const float*)d_in[13];
    const float* a14 = (const float*)d_in[14];
    const float* e_reg_sum = (in_sizes[13] == NE) ? a13 : a14;
    const float* v_reg_sum = (in_sizes[13] == NE) ? a14 : a13;

    float* out_v = (float*)d_out;
    float* out_e = (float*)d_out + (size_t)NV * NH;

    const dim3 blk(256);
    const int NB_E = (NE + 255) / 256;
    const int NB_V = (NV + 255) / 256;

    // ---- fast-path ws layout ----
    unsigned short* ev_bf = (unsigned short*)d_ws;            // [NE*NH]
    unsigned short* Ebf   = ev_bf + (size_t)NE * NH;          // [NE*NH] row-major
    int* e_cnt  = (int*)(Ebf + (size_t)NE * NH);
    int* v_cnt  = e_cnt + NE;
    int* e_cur  = v_cnt + NV;
    int* v_cur  = e_cur + NE;
    int* e_off  = v_cur + NV;
    int* v_off  = e_off + NE + 1;
    int* e_list = v_off + NV + 1;
    int* v_list = e_list + NI_TOT;
    int* e_bsum = v_list + NI_TOT;
    int* v_bsum = e_bsum + NB_E;
    unsigned short* Wt1t = (unsigned short*)(v_bsum + NB_V);  // tiled swz [4*8*8192]
    unsigned short* Wt2  = Wt1t + (size_t)4 * 8 * 8192;       // plain [NH*NH]
    unsigned short* Abft = Wt2 + (size_t)NH * NH;             // tiled swz [NT_A*8*8192]
    const size_t fast_need = (size_t)((char*)(Abft + (size_t)NT_A * 8 * 8192) - (char*)d_ws);

    if (ws_size >= fast_need && d_ws != nullptr) {
        // ---------- gld+swz GEMM1 / bf16 pipeline ----------
        transpose_cast_w_tiled<<<dim3(16, 16), blk, 0, stream>>>(W_v2e, Wt1t);
        transpose_cast_w<<<dim3(16, 16), blk, 0, stream>>>(W_e2v, Wt2);
        const int ngroups = NT_A * 128 * 64;
        cast_tile_swz<<<(ngroups + 255) / 256, blk, 0, stream>>>(v, Abft, NV, ngroups);
        const int nz = 2 * (NE + NV);
        zero_ints<<<(nz + 255) / 256, blk, 0, stream>>>(e_cnt, nz);
        hist_kernel<<<(NI_TOT + 255) / 256, blk, 0, stream>>>(
            game_idx, player_idx, e_cnt, v_cnt);
        scan_local<<<NB_E, blk, 0, stream>>>(e_cnt, e_off, e_bsum, NE);
        scan_bsums<<<1, blk, 0, stream>>>(e_bsum, NB_E);
        scan_add<<<NB_E, blk, 0, stream>>>(e_off, e_bsum, NE);
        scan_local<<<NB_V, blk, 0, stream>>>(v_cnt, v_off, v_bsum, NV);
        scan_bsums<<<1, blk, 0, stream>>>(v_bsum, NB_V);
        scan_add<<<NB_V, blk, 0, stream>>>(v_off, v_bsum, NV);
        fill_kernel<<<(NI_TOT + 255) / 256, blk, 0, stream>>>(
            game_idx, player_idx, e_off, e_cur, e_list, v_off, v_cur, v_list);
        // GEMM1 -> ve_bf parked in out_v region
        unsigned short* ve_bf = (unsigned short*)out_v;
        gemm_mfma_gld<<<dim3(NH / 128, NT_A), blk, 0, stream>>>(
            Abft, Wt1t, b_v, v_weight, ve_bf, NV);
        agg_e_bf16<<<NE, dim3(128), 0, stream>>>(
            e, ve_bf, player_idx, v_reg_weight, e_off, e_list, e_reg_sum,
            out_e, Ebf);
        gemm_mfma_bf16a_bf16out<<<dim3(NH / 128, (NE + 127) / 128), blk, 0, stream>>>(
            Ebf, Wt2, b_e, e_weight, ev_bf, NE);
        // XCD-column-split agg_v (bitwise-same per-column sums)
        agg_v_bf16_q<<<NV * 4, dim3(128), 0, stream>>>(
            v, v_weight, ev_bf, game_idx, e_reg_weight, v_off, v_list,
            v_reg_sum, out_v);
        return;
    }

    // ---- fallback ws layout (f32 CSR path) ----
    float* ev_w = (float*)d_ws;
    int* f_e_cnt  = (int*)((char*)d_ws + (size_t)NE * NH * sizeof(float));
    int* f_v_cnt  = f_e_cnt + NE;
    int* f_e_cur  = f_v_cnt + NV;
    int* f_v_cur  = f_e_cur + NE;
    int* f_e_off  = f_v_cur + NV;
    int* f_v_off  = f_e_off + NE + 1;
    int* f_e_list = f_v_off + NV + 1;
    int* f_v_list = f_e_list + NI_TOT;
    const size_t csr_need = (size_t)((char*)(f_v_list + NI_TOT) - (char*)d_ws);

    if (ws_size >= csr_need && d_ws != nullptr) {
        gemm_relu_scale<<<dim3(NH / 64, (NV + 63) / 64), blk, 0, stream>>>(
            v, W_v2e, b_v, v_weight, out_v, NV);
        const int nz = 2 * (NE + NV);
        zero_ints<<<(nz + 255) / 256, blk, 0, stream>>>(f_e_cnt, nz);
        hist_kernel<<<(NI_TOT + 255) / 256, blk, 0, stream>>>(
            game_idx, player_idx, f_e_cnt, f_v_cnt);
        scan_kernel<<<1, blk, 0, stream>>>(f_e_cnt, f_e_off, NE);
        scan_kernel<<<1, blk, 0, stream>>>(f_v_cnt, f_v_off, NV);
        fill_kernel<<<(NI_TOT + 255) / 256, blk, 0, stream>>>(
            game_idx, player_idx, f_e_off, f_e_cur, f_e_list, f_v_off, f_v_cur, f_v_list);
        agg_e_kernel<<<NE, dim3(128), 0, stream>>>(
            e, out_v, player_idx, v_reg_weight, f_e_off, f_e_list, e_reg_sum, out_e);
        gemm_relu_scale<<<dim3(NH / 64, (NE + 63) / 64), blk, 0, stream>>>(
            out_e, W_e2v, b_e, e_weight, ev_w, NE);
        agg_v_kernel<<<NV, dim3(128), 0, stream>>>(
            v, v_weight, ev_w, game_idx, e_reg_weight, f_v_off, f_v_list,
            v_reg_sum, out_v);
        return;
    }

    // ---------- atomic fallback ----------
    const size_t evw_bytes = (size_t)NE * NH * sizeof(float);
    const bool big_ws = (ws_size >= evw_bytes) && (d_ws != nullptr);
    float* ev_w2 = big_ws ? (float*)d_ws : (out_v + (size_t)PB * NH);
    const int pb = big_ws ? NV : PB;
    const int n4_e = NE * NH / 4;

    gemm_relu_scale<<<dim3(NH / 64, (NV + 63) / 64), blk, 0, stream>>>(
        v, W_v2e, b_v, v_weight, out_v, NV);
    init_copy<<<(n4_e + 255) / 256, blk, 0, stream>>>(e, out_e, n4_e);
    scatter_add_kernel<<<(NI_TOT + 1) / 2, blk, 0, stream>>>(
        out_v, player_idx, game_idx, v_reg_weight, out_e, NI_TOT, 0, NE, NV);
    div_rows<<<(n4_e + 255) / 256, blk, 0, stream>>>(e_reg_sum, out_e, n4_e);
    gemm_relu_scale<<<dim3(NH / 64, (NE + 63) / 64), blk, 0, stream>>>(
        out_e, W_e2v, b_e, e_weight, ev_w2, NE);
    {
        const int n4 = pb * NH / 4;
        init_scale_rows<<<(n4 + 255) / 256, blk, 0, stream>>>(v, v_weight, out_v, n4);
    }
    scatter_add_kernel<<<(NI_TOT + 1) / 2, blk, 0, stream>>>(
        ev_w2, game_idx, player_idx, e_reg_weight, out_v, NI_TOT, 0, pb, NE);
    {
        const int n4 = pb * NH / 4;
        div_rows<<<(n4 + 255) / 256, blk, 0, stream>>>(v_reg_sum, out_v, n4);
    }
    if (!big_ws) {
        const int n4t = (NV - PB) * NH / 4;
        init_scale_rows<<<(n4t + 255) / 256, blk, 0, stream>>>(
            v + (size_t)PB * NH, v_weight + PB, out_v + (size_t)PB * NH, n4t);
        recompute_ev_scatter<<<NI_TOT, blk, 0, stream>>>(
            out_e, W_e2v, b_e, e_weight, player_idx, game_idx, e_reg_weight,
            out_v, PB);
        div_rows<<<(n4t + 255) / 256, blk, 0, stream>>>(
            v_reg_sum + PB, out_v + (size_t)PB * NH, n4t);
    }
}

// Round 15
// 314.782 us; speedup vs baseline: 1.1971x; 1.1971x over previous
//
#include <hip/hip_runtime.h>

#define NV 50000
#define NE 10000
#define NH 512
#define NI_TOT 300000
#define PB 40000
#define NT_A 391   // ceil(NV/128) row tiles for tiled A

typedef __attribute__((ext_vector_type(8))) short short8v;    // 8 bf16
typedef __attribute__((ext_vector_type(4))) float f32x4;
typedef __attribute__((ext_vector_type(4))) unsigned short ushort4v;

__device__ __forceinline__ unsigned short f2bf(float x) {
    union { float f; unsigned int u; } v; v.f = x;
    unsigned int r = (v.u + 0x7FFFu + ((v.u >> 16) & 1u)) >> 16;   // RNE
    return (unsigned short)r;
}
__device__ __forceinline__ unsigned int pack2bf(float lo, float hi) {
    return (unsigned int)f2bf(lo) | ((unsigned int)f2bf(hi) << 16);
}
__device__ __forceinline__ float bf2f(unsigned short u) {
    union { unsigned int x; float f; } v; v.x = ((unsigned int)u) << 16;
    return v.f;
}
__device__ __forceinline__ void gload16(const void* g, void* l) {
    __builtin_amdgcn_global_load_lds(
        (const __attribute__((address_space(1))) unsigned int*)g,
        (__attribute__((address_space(3))) unsigned int*)l, 16, 0, 0);
}

// ---------------- cast v -> tiled+swizzled bf16 A (zero-padded tail rows) -------
__global__ __launch_bounds__(256) void cast_tile_swz(
    const float* __restrict__ src, unsigned short* __restrict__ dst,
    int M, int ngroups)
{
    const int i = blockIdx.x * 256 + threadIdx.x;
    if (i >= ngroups) return;
    const int r  = i >> 6;
    const int gq = i & 63;
    uint4 o = make_uint4(0u, 0u, 0u, 0u);
    if (r < M) {
        const float4 a = *reinterpret_cast<const float4*>(&src[(size_t)r * NH + gq * 8]);
        const float4 b = *reinterpret_cast<const float4*>(&src[(size_t)r * NH + gq * 8 + 4]);
        o.x = pack2bf(a.x, a.y); o.y = pack2bf(a.z, a.w);
        o.z = pack2bf(b.x, b.y); o.w = pack2bf(b.z, b.w);
    }
    const size_t base = ((size_t)(r >> 7) * 8 + (gq >> 3)) * 16384;
    const int phys = (((r & 127) * 128 + (gq & 7) * 16)) ^ ((r & 7) << 4);
    *reinterpret_cast<uint4*>((char*)dst + base + phys) = o;
}

// ---------------- both W transposes in one launch (z: 0=tiled W1, 1=plain W2) ---
__global__ __launch_bounds__(256) void transpose_cast_w_both(
    const float* __restrict__ W1, unsigned short* __restrict__ Wt1t,
    const float* __restrict__ W2, unsigned short* __restrict__ Wt2)
{
    __shared__ float t[32][33];
    const int bx = blockIdx.x;          // n tile
    const int by = blockIdx.y;          // k tile
    const int tx = threadIdx.x & 31;
    const int ty = threadIdx.x >> 5;
    const float* W = (blockIdx.z == 0) ? W1 : W2;
    #pragma unroll
    for (int j = 0; j < 32; j += 8)
        t[ty + j][tx] = W[(size_t)(by * 32 + ty + j) * NH + bx * 32 + tx];
    __syncthreads();
    if (blockIdx.z == 0) {
        #pragma unroll
        for (int j = 0; j < 32; j += 8) {
            const int n = bx * 32 + ty + j;
            const int k = by * 32 + tx;
            const size_t base = ((size_t)(n >> 7) * 8 + (k >> 6)) * 16384;
            const int phys = (((n & 127) * 128 + (k & 63) * 2)) ^ ((n & 7) << 4);
            *reinterpret_cast<unsigned short*>((char*)Wt1t + base + phys) = f2bf(t[tx][ty + j]);
        }
    } else {
        #pragma unroll
        for (int j = 0; j < 32; j += 8)
            Wt2[(size_t)(bx * 32 + ty + j) * NH + by * 32 + tx] = f2bf(t[tx][ty + j]);
    }
}

// plain transpose (fallback paths)
__global__ __launch_bounds__(256) void transpose_cast_w(
    const float* __restrict__ W, unsigned short* __restrict__ Wt)
{
    __shared__ float t[32][33];
    const int bx = blockIdx.x;
    const int by = blockIdx.y;
    const int tx = threadIdx.x & 31;
    const int ty = threadIdx.x >> 5;
    #pragma unroll
    for (int j = 0; j < 32; j += 8)
        t[ty + j][tx] = W[(size_t)(by * 32 + ty + j) * NH + bx * 32 + tx];
    __syncthreads();
    #pragma unroll
    for (int j = 0; j < 32; j += 8)
        Wt[(size_t)(bx * 32 + ty + j) * NH + by * 32 + tx] = f2bf(t[tx][ty + j]);
}

// ---------------- GEMM1: tiled-swizzled A/B via global_load_lds, bf16 out -------
__global__ __launch_bounds__(256) void gemm_mfma_gld(
    const unsigned short* __restrict__ At, const unsigned short* __restrict__ Btl,
    const float* __restrict__ bias, const float* __restrict__ rowscale,
    unsigned short* __restrict__ Cbf, int M)
{
    __shared__ __align__(16) unsigned char As[16384];
    __shared__ __align__(16) unsigned char Bs[16384];

    const int tid  = threadIdx.x;
    const int lane = tid & 63;
    const int wave = tid >> 6;
    const int wm   = (wave & 1) * 64;
    const int wn   = (wave >> 1) * 64;
    const int tileM = blockIdx.y * 128;
    const int col0  = blockIdx.x * 128;

    const char* Abase = (const char*)At  + (size_t)blockIdx.y * 8 * 16384;
    const char* Bbase = (const char*)Btl + (size_t)blockIdx.x * 8 * 16384;

    f32x4 acc[4][4] = {};

    for (int s = 0; s < 8; ++s) {
        const char* ga = Abase + s * 16384 + (size_t)wave * 4096 + lane * 16;
        const char* gb = Bbase + s * 16384 + (size_t)wave * 4096 + lane * 16;
        char* la = (char*)As + wave * 4096;
        char* lb = (char*)Bs + wave * 4096;
        #pragma unroll
        for (int i = 0; i < 4; ++i) {
            gload16(ga + i * 1024, la + i * 1024);
            gload16(gb + i * 1024, lb + i * 1024);
        }
        __syncthreads();   // drains vmcnt for global_load_lds

        #pragma unroll
        for (int ks = 0; ks < 2; ++ks) {
            const int kb = ks * 64 + (lane >> 4) * 16;
            short8v af[4], bfr[4];
            #pragma unroll
            for (int mf = 0; mf < 4; ++mf) {
                const int r = wm + mf * 16 + (lane & 15);
                af[mf] = *reinterpret_cast<const short8v*>(
                    (const char*)As + ((r * 128 + kb) ^ ((r & 7) << 4)));
            }
            #pragma unroll
            for (int nf = 0; nf < 4; ++nf) {
                const int n = wn + nf * 16 + (lane & 15);
                bfr[nf] = *reinterpret_cast<const short8v*>(
                    (const char*)Bs + ((n * 128 + kb) ^ ((n & 7) << 4)));
            }
            #pragma unroll
            for (int mf = 0; mf < 4; ++mf)
                #pragma unroll
                for (int nf = 0; nf < 4; ++nf)
                    acc[mf][nf] = __builtin_amdgcn_mfma_f32_16x16x32_bf16(
                        af[mf], bfr[nf], acc[mf][nf], 0, 0, 0);
        }
        __syncthreads();
    }

    const int rgrp = (lane >> 4) * 4;
    const int cin  = lane & 15;
    #pragma unroll
    for (int mf = 0; mf < 4; ++mf) {
        #pragma unroll
        for (int r = 0; r < 4; ++r) {
            const int row = tileM + wm + mf * 16 + rgrp + r;
            if (row < M) {
                const float rs = rowscale[row];
                #pragma unroll
                for (int nf = 0; nf < 4; ++nf) {
                    const int col = col0 + wn + nf * 16 + cin;
                    Cbf[(size_t)row * NH + col] =
                        f2bf(fmaxf(acc[mf][nf][r] + bias[col], 0.f) * rs);
                }
            }
        }
    }
}

// ---------------- GEMM2: row-major bf16 A, plain Bt, reg staging ----------------
__global__ __launch_bounds__(256) void gemm_mfma_bf16a_bf16out(
    const unsigned short* __restrict__ Abf, const unsigned short* __restrict__ Bt,
    const float* __restrict__ bias, const float* __restrict__ rowscale,
    unsigned short* __restrict__ Cbf, int M)
{
    __shared__ unsigned short As[128][72];
    __shared__ unsigned short Bs[128][72];

    const int tid  = threadIdx.x;
    const int lane = tid & 63;
    const int wave = tid >> 6;
    const int wm   = (wave & 1) * 64;
    const int wn   = (wave >> 1) * 64;
    const int tileM = blockIdx.y * 128;
    const int col0  = blockIdx.x * 128;

    f32x4 acc[4][4] = {};
    const short8v zero8 = {0, 0, 0, 0, 0, 0, 0, 0};

    for (int k0 = 0; k0 < NH; k0 += 64) {
        #pragma unroll
        for (int j = 0; j < 4; ++j) {
            const int chunk = j * 256 + tid;
            const int n  = chunk >> 3;
            const int kc = (chunk & 7) * 8;
            const int arow = tileM + n;
            short8v a = zero8;
            if (arow < M)
                a = *reinterpret_cast<const short8v*>(&Abf[(size_t)arow * NH + k0 + kc]);
            *reinterpret_cast<short8v*>(&As[n][kc]) = a;
        }
        #pragma unroll
        for (int j = 0; j < 4; ++j) {
            const int chunk = j * 256 + tid;
            const int n  = chunk >> 3;
            const int kc = (chunk & 7) * 8;
            short8v b = *reinterpret_cast<const short8v*>(
                &Bt[(size_t)(col0 + n) * NH + k0 + kc]);
            *reinterpret_cast<short8v*>(&Bs[n][kc]) = b;
        }
        __syncthreads();

        #pragma unroll
        for (int ks = 0; ks < 2; ++ks) {
            const int koff = ks * 32 + (lane >> 4) * 8;
            short8v af[4], bfr[4];
            #pragma unroll
            for (int mf = 0; mf < 4; ++mf)
                af[mf] = *reinterpret_cast<short8v*>(&As[wm + mf * 16 + (lane & 15)][koff]);
            #pragma unroll
            for (int nf = 0; nf < 4; ++nf)
                bfr[nf] = *reinterpret_cast<short8v*>(&Bs[wn + nf * 16 + (lane & 15)][koff]);
            #pragma unroll
            for (int mf = 0; mf < 4; ++mf)
                #pragma unroll
                for (int nf = 0; nf < 4; ++nf)
                    acc[mf][nf] = __builtin_amdgcn_mfma_f32_16x16x32_bf16(
                        af[mf], bfr[nf], acc[mf][nf], 0, 0, 0);
        }
        __syncthreads();
    }

    const int rgrp = (lane >> 4) * 4;
    const int cin  = lane & 15;
    #pragma unroll
    for (int mf = 0; mf < 4; ++mf) {
        #pragma unroll
        for (int r = 0; r < 4; ++r) {
            const int row = tileM + wm + mf * 16 + rgrp + r;
            if (row < M) {
                const float rs = rowscale[row];
                #pragma unroll
                for (int nf = 0; nf < 4; ++nf) {
                    const int col = col0 + wn + nf * 16 + cin;
                    Cbf[(size_t)row * NH + col] =
                        f2bf(fmaxf(acc[mf][nf][r] + bias[col], 0.f) * rs);
                }
            }
        }
    }
}

// ---------------- f32 GEMM (fallback) ----------------
__global__ __launch_bounds__(256) void gemm_relu_scale(
    const float* __restrict__ A, const float* __restrict__ B,
    const float* __restrict__ bias, const float* __restrict__ rowscale,
    float* __restrict__ C, int M)
{
    __shared__ float As[16][68];
    __shared__ float Bs[16][64];
    const int tid = threadIdx.x;
    const int tx = tid & 15;
    const int ty = tid >> 4;
    const int tileM = blockIdx.y * 64;
    const int col0  = blockIdx.x * 64;
    const int lr  = tid >> 2;
    const int lk4 = (tid & 3) * 4;
    const int bc  = tid & 63;
    const int bk  = tid >> 6;
    float acc[4][4] = {};
    for (int k0 = 0; k0 < NH; k0 += 16) {
        const int arow = tileM + lr;
        float4 av = make_float4(0.f, 0.f, 0.f, 0.f);
        if (arow < M)
            av = *reinterpret_cast<const float4*>(&A[(size_t)arow * NH + k0 + lk4]);
        As[lk4 + 0][lr] = av.x; As[lk4 + 1][lr] = av.y;
        As[lk4 + 2][lr] = av.z; As[lk4 + 3][lr] = av.w;
        #pragma unroll
        for (int jj = 0; jj < 4; ++jj) {
            const int kk = bk + jj * 4;
            Bs[kk][bc] = B[(size_t)(k0 + kk) * NH + col0 + bc];
        }
        __syncthreads();
        #pragma unroll
        for (int kk = 0; kk < 16; ++kk) {
            float4 a = *reinterpret_cast<const float4*>(&As[kk][ty * 4]);
            float4 b = *reinterpret_cast<const float4*>(&Bs[kk][tx * 4]);
            acc[0][0] += a.x * b.x; acc[0][1] += a.x * b.y; acc[0][2] += a.x * b.z; acc[0][3] += a.x * b.w;
            acc[1][0] += a.y * b.x; acc[1][1] += a.y * b.y; acc[1][2] += a.y * b.z; acc[1][3] += a.y * b.w;
            acc[2][0] += a.z * b.x; acc[2][1] += a.z * b.y; acc[2][2] += a.z * b.z; acc[2][3] += a.z * b.w;
            acc[3][0] += a.w * b.x; acc[3][1] += a.w * b.y; acc[3][2] += a.w * b.z; acc[3][3] += a.w * b.w;
        }
        __syncthreads();
    }
    const int rbase = tileM + ty * 4;
    const int cbase = col0 + tx * 4;
    #pragma unroll
    for (int i = 0; i < 4; ++i) {
        const int row = rbase + i;
        if (row < M) {
            const float s = rowscale[row];
            float4 o;
            o.x = fmaxf(acc[i][0] + bias[cbase + 0], 0.f) * s;
            o.y = fmaxf(acc[i][1] + bias[cbase + 1], 0.f) * s;
            o.z = fmaxf(acc[i][2] + bias[cbase + 2], 0.f) * s;
            o.w = fmaxf(acc[i][3] + bias[cbase + 3], 0.f) * s;
            *reinterpret_cast<float4*>(&C[(size_t)row * NH + cbase]) = o;
        }
    }
}

// ---------------- CSR build ----------------
__global__ __launch_bounds__(256) void zero_ints(int* __restrict__ p, int n)
{
    const int i = blockIdx.x * 256 + threadIdx.x;
    if (i < n) p[i] = 0;
}

__global__ __launch_bounds__(256) void hist_kernel(
    const int* __restrict__ gi, const int* __restrict__ pi,
    int* __restrict__ e_cnt, int* __restrict__ v_cnt)
{
    const int i = blockIdx.x * 256 + threadIdx.x;
    if (i >= NI_TOT) return;
    atomicAdd(&e_cnt[gi[i]], 1);
    atomicAdd(&v_cnt[pi[i]], 1);
}

__device__ __forceinline__ void scan_local_body(
    const int* cnt, int* off, int* bsum, int n, int blk)
{
    __shared__ int buf[256];
    const int t = threadIdx.x;
    const int gi = blk * 256 + t;
    int x = (gi < n) ? cnt[gi] : 0;
    buf[t] = x;
    __syncthreads();
    #pragma unroll
    for (int d = 1; d < 256; d <<= 1) {
        int y = (t >= d) ? buf[t - d] : 0;
        __syncthreads();
        buf[t] += y;
        __syncthreads();
    }
    if (gi < n) off[gi + 1] = buf[t];
    if (t == 255) bsum[blk] = buf[255];
}

// fused e+v local scans: blocks [0,NBE) -> e, [NBE, NBE+NBV) -> v
__global__ __launch_bounds__(256) void scan_local_both(
    const int* __restrict__ e_cnt, int* __restrict__ e_off, int* __restrict__ e_bsum, int ne, int nbe,
    const int* __restrict__ v_cnt, int* __restrict__ v_off, int* __restrict__ v_bsum, int nv)
{
    const int b = blockIdx.x;
    if (b < nbe) scan_local_body(e_cnt, e_off, e_bsum, ne, b);
    else         scan_local_body(v_cnt, v_off, v_bsum, nv, b - nbe);
}

__device__ __forceinline__ void scan_bsums_body(int* bsum, int nb)
{
    __shared__ int buf[256];
    const int t = threadIdx.x;
    const int x = (t < nb) ? bsum[t] : 0;
    buf[t] = x;
    __syncthreads();
    #pragma unroll
    for (int d = 1; d < 256; d <<= 1) {
        int y = (t >= d) ? buf[t - d] : 0;
        __syncthreads();
        buf[t] += y;
        __syncthreads();
    }
    if (t < nb) bsum[t] = buf[t] - x;
    __syncthreads();
}

// single block: scan e_bsum then v_bsum
__global__ __launch_bounds__(256) void scan_bsums_both(
    int* __restrict__ e_bsum, int nbe, int* __restrict__ v_bsum, int nbv)
{
    scan_bsums_body(e_bsum, nbe);
    scan_bsums_body(v_bsum, nbv);
}

// fused add: blocks [0,NBE) -> e, rest -> v
__global__ __launch_bounds__(256) void scan_add_both(
    int* __restrict__ e_off, const int* __restrict__ e_bsum, int ne, int nbe,
    int* __restrict__ v_off, const int* __restrict__ v_bsum, int nv)
{
    const int b = blockIdx.x;
    const int t = threadIdx.x;
    if (b < nbe) {
        const int gi = b * 256 + t;
        if (gi == 0) e_off[0] = 0;
        if (gi < ne) e_off[gi + 1] += e_bsum[b];
    } else {
        const int gi = (b - nbe) * 256 + t;
        if (gi == 0) v_off[0] = 0;
        if (gi < nv) v_off[gi + 1] += v_bsum[b - nbe];
    }
}

// single-block scan (fallback path only)
__global__ __launch_bounds__(256) void scan_kernel(
    const int* __restrict__ cnt, int* __restrict__ off, int n)
{
    __shared__ int buf[256];
    __shared__ int carry_s;
    const int t = threadIdx.x;
    if (t == 0) { off[0] = 0; carry_s = 0; }
    __syncthreads();
    for (int base = 0; base < n; base += 256) {
        int x = (base + t < n) ? cnt[base + t] : 0;
        buf[t] = x;
        __syncthreads();
        #pragma unroll
        for (int d = 1; d < 256; d <<= 1) {
            int y = (t >= d) ? buf[t - d] : 0;
            __syncthreads();
            buf[t] += y;
            __syncthreads();
        }
        if (base + t < n) off[base + t + 1] = buf[t] + carry_s;
        __syncthreads();
        if (t == 255) carry_s += buf[255];
        __syncthreads();
    }
}

__global__ __launch_bounds__(256) void fill_kernel(
    const int* __restrict__ gi, const int* __restrict__ pi,
    const int* __restrict__ e_off, int* __restrict__ e_cur, int* __restrict__ e_list,
    const int* __restrict__ v_off, int* __restrict__ v_cur, int* __restrict__ v_list)
{
    const int i = blockIdx.x * 256 + threadIdx.x;
    if (i >= NI_TOT) return;
    const int g = gi[i];
    e_list[e_off[g] + atomicAdd(&e_cur[g], 1)] = i;
    const int p = pi[i];
    v_list[v_off[p] + atomicAdd(&v_cur[p], 1)] = i;
}

// ---------------- bf16-gather aggregation (NT streams) ----------------
__global__ __launch_bounds__(128) void agg_e_bf16(
    const float* __restrict__ e, const unsigned short* __restrict__ ve_bf,
    const int* __restrict__ player_idx, const float* __restrict__ v_reg_weight,
    const int* __restrict__ e_off, const int* __restrict__ e_list,
    const float* __restrict__ e_reg_sum, float* __restrict__ out_e,
    unsigned short* __restrict__ Ebf)
{
    __shared__ int   sp[128];
    __shared__ float sw[128];
    const int g = blockIdx.x;
    const int t = threadIdx.x;
    const int c = t << 2;
    f32x4 acc = __builtin_nontemporal_load(
        reinterpret_cast<const f32x4*>(&e[(size_t)g * NH + c]));
    const int beg = e_off[g], end = e_off[g + 1];
    for (int base = beg; base < end; base += 128) {
        const int m = min(128, end - base);
        __syncthreads();
        if (t < m) {
            const int i = e_list[base + t];
            sp[t] = player_idx[i];
            sw[t] = v_reg_weight[i];
        }
        __syncthreads();
        #pragma unroll 4
        for (int j = 0; j < m; ++j) {
            const int   p = sp[j];
            const float w = sw[j];
            ushort4v x = *reinterpret_cast<const ushort4v*>(&ve_bf[(size_t)p * NH + c]);
            acc.x += w * bf2f(x.x); acc.y += w * bf2f(x.y);
            acc.z += w * bf2f(x.z); acc.w += w * bf2f(x.w);
        }
    }
    const float inv = 1.0f / e_reg_sum[g];
    acc.x *= inv; acc.y *= inv; acc.z *= inv; acc.w *= inv;
    __builtin_nontemporal_store(acc,
        reinterpret_cast<f32x4*>(&out_e[(size_t)g * NH + c]));
    uint2 pk;
    pk.x = pack2bf(acc.x, acc.y);
    pk.y = pack2bf(acc.z, acc.w);
    *reinterpret_cast<uint2*>(&Ebf[(size_t)g * NH + c]) = pk;    // cached: GEMM2 re-reads
}

__global__ __launch_bounds__(128) void agg_v_bf16(
    const float* __restrict__ v, const float* __restrict__ v_weight,
    const unsigned short* __restrict__ ev_bf,
    const int* __restrict__ game_idx, const float* __restrict__ e_reg_weight,
    const int* __restrict__ v_off, const int* __restrict__ v_list,
    const float* __restrict__ v_reg_sum, float* __restrict__ out_v)
{
    __shared__ int   sg[128];
    __shared__ float sw[128];
    const int p = blockIdx.x;
    const int t = threadIdx.x;
    const int c = t << 2;
    const float vw = v_weight[p];
    f32x4 acc = __builtin_nontemporal_load(
        reinterpret_cast<const f32x4*>(&v[(size_t)p * NH + c]));
    acc.x *= vw; acc.y *= vw; acc.z *= vw; acc.w *= vw;
    const int beg = v_off[p], end = v_off[p + 1];
    for (int base = beg; base < end; base += 128) {
        const int m = min(128, end - base);
        __syncthreads();
        if (t < m) {
            const int i = v_list[base + t];
            sg[t] = game_idx[i];
            sw[t] = e_reg_weight[i];
        }
        __syncthreads();
        #pragma unroll 4
        for (int j = 0; j < m; ++j) {
            const int   g = sg[j];
            const float w = sw[j];
            ushort4v x = *reinterpret_cast<const ushort4v*>(&ev_bf[(size_t)g * NH + c]);
            acc.x += w * bf2f(x.x); acc.y += w * bf2f(x.y);
            acc.z += w * bf2f(x.z); acc.w += w * bf2f(x.w);
        }
    }
    const float inv = 1.0f / v_reg_sum[p];
    acc.x *= inv; acc.y *= inv; acc.z *= inv; acc.w *= inv;
    __builtin_nontemporal_store(acc,
        reinterpret_cast<f32x4*>(&out_v[(size_t)p * NH + c]));
}

// ---------------- f32-gather aggregation (fallback) ----------------
__global__ __launch_bounds__(128) void agg_e_kernel(
    const float* __restrict__ e, const float* __restrict__ ve_w,
    const int* __restrict__ player_idx, const float* __restrict__ v_reg_weight,
    const int* __restrict__ e_off, const int* __restrict__ e_list,
    const float* __restrict__ e_reg_sum, float* __restrict__ out_e)
{
    __shared__ int   sp[128];
    __shared__ float sw[128];
    const int g = blockIdx.x;
    const int t = threadIdx.x;
    const int c = t << 2;
    float4 acc = *reinterpret_cast<const float4*>(&e[(size_t)g * NH + c]);
    const int beg = e_off[g], end = e_off[g + 1];
    for (int base = beg; base < end; base += 128) {
        const int m = min(128, end - base);
        __syncthreads();
        if (t < m) {
            const int i = e_list[base + t];
            sp[t] = player_idx[i];
            sw[t] = v_reg_weight[i];
        }
        __syncthreads();
        #pragma unroll 4
        for (int j = 0; j < m; ++j) {
            const int   p = sp[j];
            const float w = sw[j];
            float4 x = *reinterpret_cast<const float4*>(&ve_w[(size_t)p * NH + c]);
            acc.x += w * x.x; acc.y += w * x.y; acc.z += w * x.z; acc.w += w * x.w;
        }
    }
    const float inv = 1.0f / e_reg_sum[g];
    acc.x *= inv; acc.y *= inv; acc.z *= inv; acc.w *= inv;
    *reinterpret_cast<float4*>(&out_e[(size_t)g * NH + c]) = acc;
}

__global__ __launch_bounds__(128) void agg_v_kernel(
    const float* __restrict__ v, const float* __restrict__ v_weight,
    const float* __restrict__ ev_w,
    const int* __restrict__ game_idx, const float* __restrict__ e_reg_weight,
    const int* __restrict__ v_off, const int* __restrict__ v_list,
    const float* __restrict__ v_reg_sum, float* __restrict__ out_v)
{
    __shared__ int   sg[128];
    __shared__ float sw[128];
    const int p = blockIdx.x;
    const int t = threadIdx.x;
    const int c = t << 2;
    const float vw = v_weight[p];
    float4 acc = *reinterpret_cast<const float4*>(&v[(size_t)p * NH + c]);
    acc.x *= vw; acc.y *= vw; acc.z *= vw; acc.w *= vw;
    const int beg = v_off[p], end = v_off[p + 1];
    for (int base = beg; base < end; base += 128) {
        const int m = min(128, end - base);
        __syncthreads();
        if (t < m) {
            const int i = v_list[base + t];
            sg[t] = game_idx[i];
            sw[t] = e_reg_weight[i];
        }
        __syncthreads();
        #pragma unroll 4
        for (int j = 0; j < m; ++j) {
            const int   g = sg[j];
            const float w = sw[j];
            float4 x = *reinterpret_cast<const float4*>(&ev_w[(size_t)g * NH + c]);
            acc.x += w * x.x; acc.y += w * x.y; acc.z += w * x.z; acc.w += w * x.w;
        }
    }
    const float inv = 1.0f / v_reg_sum[p];
    acc.x *= inv; acc.y *= inv; acc.z *= inv; acc.w *= inv;
    *reinterpret_cast<float4*>(&out_v[(size_t)p * NH + c]) = acc;
}

// ---------------- atomic-path fallback kernels ----------------
__global__ __launch_bounds__(256) void scatter_add_kernel(
    const float* __restrict__ src, const int* __restrict__ gidx,
    const int* __restrict__ sidx, const float* __restrict__ regw,
    float* __restrict__ dst, int ni, int smin, int smax, int gmax)
{
    const int i = blockIdx.x * 2 + (threadIdx.x >> 7);
    if (i >= ni) return;
    const int s = sidx[i];
    if (s < smin || s >= smax) return;
    const int g = gidx[i];
    if (g < 0 || g >= gmax) return;
    const int c = (threadIdx.x & 127) << 2;
    const float w = regw[i];
    float4 val = *reinterpret_cast<const float4*>(&src[(size_t)g * NH + c]);
    float* d = &dst[(size_t)s * NH + c];
    atomicAdd(d + 0, val.x * w);
    atomicAdd(d + 1, val.y * w);
    atomicAdd(d + 2, val.z * w);
    atomicAdd(d + 3, val.w * w);
}

__global__ __launch_bounds__(256) void recompute_ev_scatter(
    const float* __restrict__ e_out, const float* __restrict__ W,
    const float* __restrict__ bias, const float* __restrict__ e_weight,
    const int* __restrict__ player_idx, const int* __restrict__ game_idx,
    const float* __restrict__ e_reg_weight, float* __restrict__ out_v, int pmin)
{
    const int i = blockIdx.x;
    const int p = player_idx[i];
    if (p < pmin || p >= NV) return;
    const int g = game_idx[i];
    if (g < 0 || g >= NE) return;
    __shared__ float eg[NH];
    const int t = threadIdx.x;
    eg[t]       = e_out[(size_t)g * NH + t];
    eg[t + 256] = e_out[(size_t)g * NH + t + 256];
    __syncthreads();
    float s0 = 0.f, s1 = 0.f;
    #pragma unroll 4
    for (int k = 0; k < NH; ++k) {
        const float ek = eg[k];
        s0 += ek * W[(size_t)k * NH + t];
        s1 += ek * W[(size_t)k * NH + t + 256];
    }
    const float ew = e_weight[g] * e_reg_weight[i];
    atomicAdd(&out_v[(size_t)p * NH + t],       fmaxf(s0 + bias[t], 0.f) * ew);
    atomicAdd(&out_v[(size_t)p * NH + t + 256], fmaxf(s1 + bias[t + 256], 0.f) * ew);
}

__global__ __launch_bounds__(256) void init_copy(
    const float* __restrict__ src, float* __restrict__ dst, int n4)
{
    const int i = blockIdx.x * 256 + threadIdx.x;
    if (i < n4)
        reinterpret_cast<float4*>(dst)[i] = reinterpret_cast<const float4*>(src)[i];
}

__global__ __launch_bounds__(256) void init_scale_rows(
    const float* __restrict__ src, const float* __restrict__ w,
    float* __restrict__ dst, int n4)
{
    const int i = blockIdx.x * 256 + threadIdx.x;
    if (i >= n4) return;
    const int row = i >> 7;
    const float s = w[row];
    float4 v = reinterpret_cast<const float4*>(src)[i];
    v.x *= s; v.y *= s; v.z *= s; v.w *= s;
    reinterpret_cast<float4*>(dst)[i] = v;
}

__global__ __launch_bounds__(256) void div_rows(
    const float* __restrict__ rs, float* __restrict__ x, int n4)
{
    const int i = blockIdx.x * 256 + threadIdx.x;
    if (i >= n4) return;
    const int row = i >> 7;
    const float inv = 1.0f / rs[row];
    float4 v = reinterpret_cast<float4*>(x)[i];
    v.x *= inv; v.y *= inv; v.z *= inv; v.w *= inv;
    reinterpret_cast<float4*>(x)[i] = v;
}

extern "C" void kernel_launch(void* const* d_in, const int* in_sizes, int n_in,
                              void* d_out, int out_size, void* d_ws, size_t ws_size,
                              hipStream_t stream) {
    const float* v            = (const float*)d_in[0];
    const float* e            = (const float*)d_in[1];
    const int*   player_idx   = (const int*)d_in[2];
    const int*   game_idx     = (const int*)d_in[3];
    const float* W_v2e        = (const float*)d_in[5];
    const float* W_e2v        = (const float*)d_in[6];
    const float* b_v          = (const float*)d_in[7];
    const float* b_e          = (const float*)d_in[8];

    const float* a9  = (const float*)d_in[9];
    const float* a10 = (const float*)d_in[10];
    const float* v_weight = (in_sizes[9]  == NV) ? a9  : a10;
    const float* e_weight = (in_sizes[9]  == NV) ? a10 : a9;
    const float* v_reg_weight = (const float*)d_in[11];
    const float* e_reg_weight = (const float*)d_in[12];
    const float* a13 = (const float*)d_in[13];
    const float* a14 = (const float*)d_in[14];
    const float* e_reg_sum = (in_sizes[13] == NE) ? a13 : a14;
    const float* v_reg_sum = (in_sizes[13] == NE) ? a14 : a13;

    float* out_v = (float*)d_out;
    float* out_e = (float*)d_out + (size_t)NV * NH;

    const dim3 blk(256);
    const int NB_E = (NE + 255) / 256;    // 40
    const int NB_V = (NV + 255) / 256;    // 196

    // ---- fast-path ws layout ----
    unsigned short* ev_bf = (unsigned short*)d_ws;            // [NE*NH]
    unsigned short* Ebf   = ev_bf + (size_t)NE * NH;          // [NE*NH] row-major
    int* e_cnt  = (int*)(Ebf + (size_t)NE * NH);
    int* v_cnt  = e_cnt + NE;
    int* e_cur  = v_cnt + NV;
    int* v_cur  = e_cur + NE;
    int* e_off  = v_cur + NV;
    int* v_off  = e_off + NE + 1;
    int* e_list = v_off + NV + 1;
    int* v_list = e_list + NI_TOT;
    int* e_bsum = v_list + NI_TOT;
    int* v_bsum = e_bsum + NB_E;
    unsigned short* Wt1t = (unsigned short*)(v_bsum + NB_V);  // tiled swz [4*8*8192]
    unsigned short* Wt2  = Wt1t + (size_t)4 * 8 * 8192;       // plain [NH*NH]
    unsigned short* Abft = Wt2 + (size_t)NH * NH;             // tiled swz [NT_A*8*8192]
    const size_t fast_need = (size_t)((char*)(Abft + (size_t)NT_A * 8 * 8192) - (char*)d_ws);

    if (ws_size >= fast_need && d_ws != nullptr) {
        // ---------- gld+swz GEMM1 / bf16 pipeline ----------
        transpose_cast_w_both<<<dim3(16, 16, 2), blk, 0, stream>>>(
            W_v2e, Wt1t, W_e2v, Wt2);
        const int ngroups = NT_A * 128 * 64;
        cast_tile_swz<<<(ngroups + 255) / 256, blk, 0, stream>>>(v, Abft, NV, ngroups);
        // zero counters (contiguous region e_cnt..v_cur = 2*(NE+NV) ints)
        hipMemsetAsync(e_cnt, 0, sizeof(int) * 2 * (NE + NV), stream);
        hist_kernel<<<(NI_TOT + 255) / 256, blk, 0, stream>>>(
            game_idx, player_idx, e_cnt, v_cnt);
        scan_local_both<<<NB_E + NB_V, blk, 0, stream>>>(
            e_cnt, e_off, e_bsum, NE, NB_E, v_cnt, v_off, v_bsum, NV);
        scan_bsums_both<<<1, blk, 0, stream>>>(e_bsum, NB_E, v_bsum, NB_V);
        scan_add_both<<<NB_E + NB_V, blk, 0, stream>>>(
            e_off, e_bsum, NE, NB_E, v_off, v_bsum, NV);
        fill_kernel<<<(NI_TOT + 255) / 256, blk, 0, stream>>>(
            game_idx, player_idx, e_off, e_cur, e_list, v_off, v_cur, v_list);
        // GEMM1 -> ve_bf parked in out_v region
        unsigned short* ve_bf = (unsigned short*)out_v;
        gemm_mfma_gld<<<dim3(NH / 128, NT_A), blk, 0, stream>>>(
            Abft, Wt1t, b_v, v_weight, ve_bf, NV);
        agg_e_bf16<<<NE, dim3(128), 0, stream>>>(
            e, ve_bf, player_idx, v_reg_weight, e_off, e_list, e_reg_sum,
            out_e, Ebf);
        gemm_mfma_bf16a_bf16out<<<dim3(NH / 128, (NE + 127) / 128), blk, 0, stream>>>(
            Ebf, Wt2, b_e, e_weight, ev_bf, NE);
        agg_v_bf16<<<NV, dim3(128), 0, stream>>>(
            v, v_weight, ev_bf, game_idx, e_reg_weight, v_off, v_list,
            v_reg_sum, out_v);
        return;
    }

    // ---- fallback ws layout (f32 CSR path) ----
    float* ev_w = (float*)d_ws;
    int* f_e_cnt  = (int*)((char*)d_ws + (size_t)NE * NH * sizeof(float));
    int* f_v_cnt  = f_e_cnt + NE;
    int* f_e_cur  = f_v_cnt + NV;
    int* f_v_cur  = f_e_cur + NE;
    int* f_e_off  = f_v_cur + NV;
    int* f_v_off  = f_e_off + NE + 1;
    int* f_e_list = f_v_off + NV + 1;
    int* f_v_list = f_e_list + NI_TOT;
    const size_t csr_need = (size_t)((char*)(f_v_list + NI_TOT) - (char*)d_ws);

    if (ws_size >= csr_need && d_ws != nullptr) {
        gemm_relu_scale<<<dim3(NH / 64, (NV + 63) / 64), blk, 0, stream>>>(
            v, W_v2e, b_v, v_weight, out_v, NV);
        const int nz = 2 * (NE + NV);
        zero_ints<<<(nz + 255) / 256, blk, 0, stream>>>(f_e_cnt, nz);
        hist_kernel<<<(NI_TOT + 255) / 256, blk, 0, stream>>>(
            game_idx, player_idx, f_e_cnt, f_v_cnt);
        scan_kernel<<<1, blk, 0, stream>>>(f_e_cnt, f_e_off, NE);
        scan_kernel<<<1, blk, 0, stream>>>(f_v_cnt, f_v_off, NV);
        fill_kernel<<<(NI_TOT + 255) / 256, blk, 0, stream>>>(
            game_idx, player_idx, f_e_off, f_e_cur, f_e_list, f_v_off, f_v_cur, f_v_list);
        agg_e_kernel<<<NE, dim3(128), 0, stream>>>(
            e, out_v, player_idx, v_reg_weight, f_e_off, f_e_list, e_reg_sum, out_e);
        gemm_relu_scale<<<dim3(NH / 64, (NE + 63) / 64), blk, 0, stream>>>(
            out_e, W_e2v, b_e, e_weight, ev_w, NE);
        agg_v_kernel<<<NV, dim3(128), 0, stream>>>(
            v, v_weight, ev_w, game_idx, e_reg_weight, f_v_off, f_v_list,
            v_reg_sum, out_v);
        return;
    }

    // ---------- atomic fallback ----------
    const size_t evw_bytes = (size_t)NE * NH * sizeof(float);
    const bool big_ws = (ws_size >= evw_bytes) && (d_ws != nullptr);
    float* ev_w2 = big_ws ? (float*)d_ws : (out_v + (size_t)PB * NH);
    const int pb = big_ws ? NV : PB;
    const int n4_e = NE * NH / 4;

    gemm_relu_scale<<<dim3(NH / 64, (NV + 63) / 64), blk, 0, stream>>>(
        v, W_v2e, b_v, v_weight, out_v, NV);
    init_copy<<<(n4_e + 255) / 256, blk, 0, stream>>>(e, out_e, n4_e);
    scatter_add_kernel<<<(NI_TOT + 1) / 2, blk, 0, stream>>>(
        out_v, player_idx, game_idx, v_reg_weight, out_e, NI_TOT, 0, NE, NV);
    div_rows<<<(n4_e + 255) / 256, blk, 0, stream>>>(e_reg_sum, out_e, n4_e);
    gemm_relu_scale<<<dim3(NH / 64, (NE + 63) / 64), blk, 0, stream>>>(
        out_e, W_e2v, b_e, e_weight, ev_w2, NE);
    {
        const int n4 = pb * NH / 4;
        init_scale_rows<<<(n4 + 255) / 256, blk, 0, stream>>>(v, v_weight, out_v, n4);
    }
    scatter_add_kernel<<<(NI_TOT + 1) / 2, blk, 0, stream>>>(
        ev_w2, game_idx, player_idx, e_reg_weight, out_v, NI_TOT, 0, pb, NE);
    {
        const int n4 = pb * NH / 4;
        div_rows<<<(n4 + 255) / 256, blk, 0, stream>>>(v_reg_sum, out_v, n4);
    }
    if (!big_ws) {
        const int n4t = (NV - PB) * NH / 4;
        init_scale_rows<<<(n4t + 255) / 256, blk, 0, stream>>>(
            v + (size_t)PB * NH, v_weight + PB, out_v + (size_t)PB * NH, n4t);
        recompute_ev_scatter<<<NI_TOT, blk, 0, stream>>>(
            out_e, W_e2v, b_e, e_weight, player_idx, game_idx, e_reg_weight,
            out_v, PB);
        div_rows<<<(n4t + 255) / 256, blk, 0, stream>>>(
            v_reg_sum + PB, out_v + (size_t)PB * NH, n4t);
    }
}

// Round 16
// 307.359 us; speedup vs baseline: 1.2260x; 1.0242x over previous
//
#include <hip/hip_runtime.h>

#define NV 50000
#define NE 10000
#define NH 512
#define NI_TOT 300000
#define PB 40000
#define NT_A 391   // ceil(NV/128) row tiles for tiled A

typedef __attribute__((ext_vector_type(8))) short short8v;    // 8 bf16
typedef __attribute__((ext_vector_type(4))) float f32x4;
typedef __attribute__((ext_vector_type(4))) unsigned short ushort4v;

__device__ __forceinline__ unsigned short f2bf(float x) {
    union { float f; unsigned int u; } v; v.f = x;
    unsigned int r = (v.u + 0x7FFFu + ((v.u >> 16) & 1u)) >> 16;   // RNE
    return (unsigned short)r;
}
__device__ __forceinline__ unsigned int pack2bf(float lo, float hi) {
    return (unsigned int)f2bf(lo) | ((unsigned int)f2bf(hi) << 16);
}
__device__ __forceinline__ float bf2f(unsigned short u) {
    union { unsigned int x; float f; } v; v.x = ((unsigned int)u) << 16;
    return v.f;
}
__device__ __forceinline__ void gload16(const void* g, void* l) {
    __builtin_amdgcn_global_load_lds(
        (const __attribute__((address_space(1))) unsigned int*)g,
        (__attribute__((address_space(3))) unsigned int*)l, 16, 0, 0);
}

// ---------------- cast v -> tiled+swizzled bf16 A (zero-padded tail rows) -------
__global__ __launch_bounds__(256) void cast_tile_swz(
    const float* __restrict__ src, unsigned short* __restrict__ dst,
    int M, int ngroups)
{
    const int i = blockIdx.x * 256 + threadIdx.x;
    if (i >= ngroups) return;
    const int r  = i >> 6;
    const int gq = i & 63;
    uint4 o = make_uint4(0u, 0u, 0u, 0u);
    if (r < M) {
        const float4 a = *reinterpret_cast<const float4*>(&src[(size_t)r * NH + gq * 8]);
        const float4 b = *reinterpret_cast<const float4*>(&src[(size_t)r * NH + gq * 8 + 4]);
        o.x = pack2bf(a.x, a.y); o.y = pack2bf(a.z, a.w);
        o.z = pack2bf(b.x, b.y); o.w = pack2bf(b.z, b.w);
    }
    const size_t base = ((size_t)(r >> 7) * 8 + (gq >> 3)) * 16384;
    const int phys = (((r & 127) * 128 + (gq & 7) * 16)) ^ ((r & 7) << 4);
    *reinterpret_cast<uint4*>((char*)dst + base + phys) = o;
}

// ---------------- both W transposes in one launch (z: 0=tiled W1, 1=plain W2) ---
__global__ __launch_bounds__(256) void transpose_cast_w_both(
    const float* __restrict__ W1, unsigned short* __restrict__ Wt1t,
    const float* __restrict__ W2, unsigned short* __restrict__ Wt2)
{
    __shared__ float t[32][33];
    const int bx = blockIdx.x;          // n tile
    const int by = blockIdx.y;          // k tile
    const int tx = threadIdx.x & 31;
    const int ty = threadIdx.x >> 5;
    const float* W = (blockIdx.z == 0) ? W1 : W2;
    #pragma unroll
    for (int j = 0; j < 32; j += 8)
        t[ty + j][tx] = W[(size_t)(by * 32 + ty + j) * NH + bx * 32 + tx];
    __syncthreads();
    if (blockIdx.z == 0) {
        #pragma unroll
        for (int j = 0; j < 32; j += 8) {
            const int n = bx * 32 + ty + j;
            const int k = by * 32 + tx;
            const size_t base = ((size_t)(n >> 7) * 8 + (k >> 6)) * 16384;
            const int phys = (((n & 127) * 128 + (k & 63) * 2)) ^ ((n & 7) << 4);
            *reinterpret_cast<unsigned short*>((char*)Wt1t + base + phys) = f2bf(t[tx][ty + j]);
        }
    } else {
        #pragma unroll
        for (int j = 0; j < 32; j += 8)
            Wt2[(size_t)(bx * 32 + ty + j) * NH + by * 32 + tx] = f2bf(t[tx][ty + j]);
    }
}

// plain transpose (fallback paths)
__global__ __launch_bounds__(256) void transpose_cast_w(
    const float* __restrict__ W, unsigned short* __restrict__ Wt)
{
    __shared__ float t[32][33];
    const int bx = blockIdx.x;
    const int by = blockIdx.y;
    const int tx = threadIdx.x & 31;
    const int ty = threadIdx.x >> 5;
    #pragma unroll
    for (int j = 0; j < 32; j += 8)
        t[ty + j][tx] = W[(size_t)(by * 32 + ty + j) * NH + bx * 32 + tx];
    __syncthreads();
    #pragma unroll
    for (int j = 0; j < 32; j += 8)
        Wt[(size_t)(bx * 32 + ty + j) * NH + by * 32 + tx] = f2bf(t[tx][ty + j]);
}

// ---------------- GEMM1: tiled-swizzled A/B via global_load_lds, bf16 out -------
// 1D grid with bijective XCD swizzle: each XCD owns contiguous (row,col) chunk.
__global__ __launch_bounds__(256) void gemm_mfma_gld(
    const unsigned short* __restrict__ At, const unsigned short* __restrict__ Btl,
    const float* __restrict__ bias, const float* __restrict__ rowscale,
    unsigned short* __restrict__ Cbf, int M)
{
    __shared__ __align__(16) unsigned char As[16384];
    __shared__ __align__(16) unsigned char Bs[16384];

    // bijective XCD remap (m204 variant): nwg = NT_A*4 = 8q+r
    const int nwg = NT_A * 4;
    const int bid = blockIdx.x;
    const int xcd = bid & 7;
    const int idx = bid >> 3;
    const int q = nwg >> 3, r = nwg & 7;
    const int wgid = (xcd < r ? xcd * (q + 1) : r * (q + 1) + (xcd - r) * q) + idx;
    const int rowt = wgid >> 2;
    const int colt = wgid & 3;

    const int tid  = threadIdx.x;
    const int lane = tid & 63;
    const int wave = tid >> 6;
    const int wm   = (wave & 1) * 64;
    const int wn   = (wave >> 1) * 64;
    const int tileM = rowt * 128;
    const int col0  = colt * 128;

    const char* Abase = (const char*)At  + (size_t)rowt * 8 * 16384;
    const char* Bbase = (const char*)Btl + (size_t)colt * 8 * 16384;

    f32x4 acc[4][4] = {};

    for (int s = 0; s < 8; ++s) {
        const char* ga = Abase + s * 16384 + (size_t)wave * 4096 + lane * 16;
        const char* gb = Bbase + s * 16384 + (size_t)wave * 4096 + lane * 16;
        char* la = (char*)As + wave * 4096;
        char* lb = (char*)Bs + wave * 4096;
        #pragma unroll
        for (int i = 0; i < 4; ++i) {
            gload16(ga + i * 1024, la + i * 1024);
            gload16(gb + i * 1024, lb + i * 1024);
        }
        __syncthreads();   // drains vmcnt for global_load_lds

        #pragma unroll
        for (int ks = 0; ks < 2; ++ks) {
            const int kb = ks * 64 + (lane >> 4) * 16;
            short8v af[4], bfr[4];
            #pragma unroll
            for (int mf = 0; mf < 4; ++mf) {
                const int rr = wm + mf * 16 + (lane & 15);
                af[mf] = *reinterpret_cast<const short8v*>(
                    (const char*)As + ((rr * 128 + kb) ^ ((rr & 7) << 4)));
            }
            #pragma unroll
            for (int nf = 0; nf < 4; ++nf) {
                const int n = wn + nf * 16 + (lane & 15);
                bfr[nf] = *reinterpret_cast<const short8v*>(
                    (const char*)Bs + ((n * 128 + kb) ^ ((n & 7) << 4)));
            }
            #pragma unroll
            for (int mf = 0; mf < 4; ++mf)
                #pragma unroll
                for (int nf = 0; nf < 4; ++nf)
                    acc[mf][nf] = __builtin_amdgcn_mfma_f32_16x16x32_bf16(
                        af[mf], bfr[nf], acc[mf][nf], 0, 0, 0);
        }
        __syncthreads();
    }

    const int rgrp = (lane >> 4) * 4;
    const int cin  = lane & 15;
    #pragma unroll
    for (int mf = 0; mf < 4; ++mf) {
        #pragma unroll
        for (int rr = 0; rr < 4; ++rr) {
            const int row = tileM + wm + mf * 16 + rgrp + rr;
            if (row < M) {
                const float rs = rowscale[row];
                #pragma unroll
                for (int nf = 0; nf < 4; ++nf) {
                    const int col = col0 + wn + nf * 16 + cin;
                    Cbf[(size_t)row * NH + col] =
                        f2bf(fmaxf(acc[mf][nf][rr] + bias[col], 0.f) * rs);
                }
            }
        }
    }
}

// ---------------- GEMM2: row-major bf16 A, plain Bt, reg staging ----------------
__global__ __launch_bounds__(256) void gemm_mfma_bf16a_bf16out(
    const unsigned short* __restrict__ Abf, const unsigned short* __restrict__ Bt,
    const float* __restrict__ bias, const float* __restrict__ rowscale,
    unsigned short* __restrict__ Cbf, int M)
{
    __shared__ unsigned short As[128][72];
    __shared__ unsigned short Bs[128][72];

    const int tid  = threadIdx.x;
    const int lane = tid & 63;
    const int wave = tid >> 6;
    const int wm   = (wave & 1) * 64;
    const int wn   = (wave >> 1) * 64;
    const int tileM = blockIdx.y * 128;
    const int col0  = blockIdx.x * 128;

    f32x4 acc[4][4] = {};
    const short8v zero8 = {0, 0, 0, 0, 0, 0, 0, 0};

    for (int k0 = 0; k0 < NH; k0 += 64) {
        #pragma unroll
        for (int j = 0; j < 4; ++j) {
            const int chunk = j * 256 + tid;
            const int n  = chunk >> 3;
            const int kc = (chunk & 7) * 8;
            const int arow = tileM + n;
            short8v a = zero8;
            if (arow < M)
                a = *reinterpret_cast<const short8v*>(&Abf[(size_t)arow * NH + k0 + kc]);
            *reinterpret_cast<short8v*>(&As[n][kc]) = a;
        }
        #pragma unroll
        for (int j = 0; j < 4; ++j) {
            const int chunk = j * 256 + tid;
            const int n  = chunk >> 3;
            const int kc = (chunk & 7) * 8;
            short8v b = *reinterpret_cast<const short8v*>(
                &Bt[(size_t)(col0 + n) * NH + k0 + kc]);
            *reinterpret_cast<short8v*>(&Bs[n][kc]) = b;
        }
        __syncthreads();

        #pragma unroll
        for (int ks = 0; ks < 2; ++ks) {
            const int koff = ks * 32 + (lane >> 4) * 8;
            short8v af[4], bfr[4];
            #pragma unroll
            for (int mf = 0; mf < 4; ++mf)
                af[mf] = *reinterpret_cast<short8v*>(&As[wm + mf * 16 + (lane & 15)][koff]);
            #pragma unroll
            for (int nf = 0; nf < 4; ++nf)
                bfr[nf] = *reinterpret_cast<short8v*>(&Bs[wn + nf * 16 + (lane & 15)][koff]);
            #pragma unroll
            for (int mf = 0; mf < 4; ++mf)
                #pragma unroll
                for (int nf = 0; nf < 4; ++nf)
                    acc[mf][nf] = __builtin_amdgcn_mfma_f32_16x16x32_bf16(
                        af[mf], bfr[nf], acc[mf][nf], 0, 0, 0);
        }
        __syncthreads();
    }

    const int rgrp = (lane >> 4) * 4;
    const int cin  = lane & 15;
    #pragma unroll
    for (int mf = 0; mf < 4; ++mf) {
        #pragma unroll
        for (int r = 0; r < 4; ++r) {
            const int row = tileM + wm + mf * 16 + rgrp + r;
            if (row < M) {
                const float rs = rowscale[row];
                #pragma unroll
                for (int nf = 0; nf < 4; ++nf) {
                    const int col = col0 + wn + nf * 16 + cin;
                    Cbf[(size_t)row * NH + col] =
                        f2bf(fmaxf(acc[mf][nf][r] + bias[col], 0.f) * rs);
                }
            }
        }
    }
}

// ---------------- f32 GEMM (fallback) ----------------
__global__ __launch_bounds__(256) void gemm_relu_scale(
    const float* __restrict__ A, const float* __restrict__ B,
    const float* __restrict__ bias, const float* __restrict__ rowscale,
    float* __restrict__ C, int M)
{
    __shared__ float As[16][68];
    __shared__ float Bs[16][64];
    const int tid = threadIdx.x;
    const int tx = tid & 15;
    const int ty = tid >> 4;
    const int tileM = blockIdx.y * 64;
    const int col0  = blockIdx.x * 64;
    const int lr  = tid >> 2;
    const int lk4 = (tid & 3) * 4;
    const int bc  = tid & 63;
    const int bk  = tid >> 6;
    float acc[4][4] = {};
    for (int k0 = 0; k0 < NH; k0 += 16) {
        const int arow = tileM + lr;
        float4 av = make_float4(0.f, 0.f, 0.f, 0.f);
        if (arow < M)
            av = *reinterpret_cast<const float4*>(&A[(size_t)arow * NH + k0 + lk4]);
        As[lk4 + 0][lr] = av.x; As[lk4 + 1][lr] = av.y;
        As[lk4 + 2][lr] = av.z; As[lk4 + 3][lr] = av.w;
        #pragma unroll
        for (int jj = 0; jj < 4; ++jj) {
            const int kk = bk + jj * 4;
            Bs[kk][bc] = B[(size_t)(k0 + kk) * NH + col0 + bc];
        }
        __syncthreads();
        #pragma unroll
        for (int kk = 0; kk < 16; ++kk) {
            float4 a = *reinterpret_cast<const float4*>(&As[kk][ty * 4]);
            float4 b = *reinterpret_cast<const float4*>(&Bs[kk][tx * 4]);
            acc[0][0] += a.x * b.x; acc[0][1] += a.x * b.y; acc[0][2] += a.x * b.z; acc[0][3] += a.x * b.w;
            acc[1][0] += a.y * b.x; acc[1][1] += a.y * b.y; acc[1][2] += a.y * b.z; acc[1][3] += a.y * b.w;
            acc[2][0] += a.z * b.x; acc[2][1] += a.z * b.y; acc[2][2] += a.z * b.z; acc[2][3] += a.z * b.w;
            acc[3][0] += a.w * b.x; acc[3][1] += a.w * b.y; acc[3][2] += a.w * b.z; acc[3][3] += a.w * b.w;
        }
        __syncthreads();
    }
    const int rbase = tileM + ty * 4;
    const int cbase = col0 + tx * 4;
    #pragma unroll
    for (int i = 0; i < 4; ++i) {
        const int row = rbase + i;
        if (row < M) {
            const float s = rowscale[row];
            float4 o;
            o.x = fmaxf(acc[i][0] + bias[cbase + 0], 0.f) * s;
            o.y = fmaxf(acc[i][1] + bias[cbase + 1], 0.f) * s;
            o.z = fmaxf(acc[i][2] + bias[cbase + 2], 0.f) * s;
            o.w = fmaxf(acc[i][3] + bias[cbase + 3], 0.f) * s;
            *reinterpret_cast<float4*>(&C[(size_t)row * NH + cbase]) = o;
        }
    }
}

// ---------------- CSR build ----------------
__global__ __launch_bounds__(256) void zero_ints(int* __restrict__ p, int n)
{
    const int i = blockIdx.x * 256 + threadIdx.x;
    if (i < n) p[i] = 0;
}

__global__ __launch_bounds__(256) void hist_kernel(
    const int* __restrict__ gi, const int* __restrict__ pi,
    int* __restrict__ e_cnt, int* __restrict__ v_cnt)
{
    const int i = blockIdx.x * 256 + threadIdx.x;
    if (i >= NI_TOT) return;
    atomicAdd(&e_cnt[gi[i]], 1);
    atomicAdd(&v_cnt[pi[i]], 1);
}

__device__ __forceinline__ void scan_local_body(
    const int* cnt, int* off, int* bsum, int n, int blk)
{
    __shared__ int buf[256];
    const int t = threadIdx.x;
    const int gi = blk * 256 + t;
    int x = (gi < n) ? cnt[gi] : 0;
    buf[t] = x;
    __syncthreads();
    #pragma unroll
    for (int d = 1; d < 256; d <<= 1) {
        int y = (t >= d) ? buf[t - d] : 0;
        __syncthreads();
        buf[t] += y;
        __syncthreads();
    }
    if (gi < n) off[gi + 1] = buf[t];
    if (t == 255) bsum[blk] = buf[255];
}

__global__ __launch_bounds__(256) void scan_local_both(
    const int* __restrict__ e_cnt, int* __restrict__ e_off, int* __restrict__ e_bsum, int ne, int nbe,
    const int* __restrict__ v_cnt, int* __restrict__ v_off, int* __restrict__ v_bsum, int nv)
{
    const int b = blockIdx.x;
    if (b < nbe) scan_local_body(e_cnt, e_off, e_bsum, ne, b);
    else         scan_local_body(v_cnt, v_off, v_bsum, nv, b - nbe);
}

__device__ __forceinline__ void scan_bsums_body(int* bsum, int nb)
{
    __shared__ int buf[256];
    const int t = threadIdx.x;
    const int x = (t < nb) ? bsum[t] : 0;
    buf[t] = x;
    __syncthreads();
    #pragma unroll
    for (int d = 1; d < 256; d <<= 1) {
        int y = (t >= d) ? buf[t - d] : 0;
        __syncthreads();
        buf[t] += y;
        __syncthreads();
    }
    if (t < nb) bsum[t] = buf[t] - x;
    __syncthreads();
}

__global__ __launch_bounds__(256) void scan_bsums_both(
    int* __restrict__ e_bsum, int nbe, int* __restrict__ v_bsum, int nbv)
{
    scan_bsums_body(e_bsum, nbe);
    scan_bsums_body(v_bsum, nbv);
}

__global__ __launch_bounds__(256) void scan_add_both(
    int* __restrict__ e_off, const int* __restrict__ e_bsum, int ne, int nbe,
    int* __restrict__ v_off, const int* __restrict__ v_bsum, int nv)
{
    const int b = blockIdx.x;
    const int t = threadIdx.x;
    if (b < nbe) {
        const int gi = b * 256 + t;
        if (gi == 0) e_off[0] = 0;
        if (gi < ne) e_off[gi + 1] += e_bsum[b];
    } else {
        const int gi = (b - nbe) * 256 + t;
        if (gi == 0) v_off[0] = 0;
        if (gi < nv) v_off[gi + 1] += v_bsum[b - nbe];
    }
}

__global__ __launch_bounds__(256) void scan_kernel(
    const int* __restrict__ cnt, int* __restrict__ off, int n)
{
    __shared__ int buf[256];
    __shared__ int carry_s;
    const int t = threadIdx.x;
    if (t == 0) { off[0] = 0; carry_s = 0; }
    __syncthreads();
    for (int base = 0; base < n; base += 256) {
        int x = (base + t < n) ? cnt[base + t] : 0;
        buf[t] = x;
        __syncthreads();
        #pragma unroll
        for (int d = 1; d < 256; d <<= 1) {
            int y = (t >= d) ? buf[t - d] : 0;
            __syncthreads();
            buf[t] += y;
            __syncthreads();
        }
        if (base + t < n) off[base + t + 1] = buf[t] + carry_s;
        __syncthreads();
        if (t == 255) carry_s += buf[255];
        __syncthreads();
    }
}

__global__ __launch_bounds__(256) void fill_kernel(
    const int* __restrict__ gi, const int* __restrict__ pi,
    const int* __restrict__ e_off, int* __restrict__ e_cur, int* __restrict__ e_list,
    const int* __restrict__ v_off, int* __restrict__ v_cur, int* __restrict__ v_list)
{
    const int i = blockIdx.x * 256 + threadIdx.x;
    if (i >= NI_TOT) return;
    const int g = gi[i];
    e_list[e_off[g] + atomicAdd(&e_cur[g], 1)] = i;
    const int p = pi[i];
    v_list[v_off[p] + atomicAdd(&v_cur[p], 1)] = i;
}

// ---------------- bf16-gather aggregation (NT streams) ----------------
__global__ __launch_bounds__(128) void agg_e_bf16(
    const float* __restrict__ e, const unsigned short* __restrict__ ve_bf,
    const int* __restrict__ player_idx, const float* __restrict__ v_reg_weight,
    const int* __restrict__ e_off, const int* __restrict__ e_list,
    const float* __restrict__ e_reg_sum, float* __restrict__ out_e,
    unsigned short* __restrict__ Ebf)
{
    __shared__ int   sp[128];
    __shared__ float sw[128];
    const int g = blockIdx.x;
    const int t = threadIdx.x;
    const int c = t << 2;
    f32x4 acc = __builtin_nontemporal_load(
        reinterpret_cast<const f32x4*>(&e[(size_t)g * NH + c]));
    const int beg = e_off[g], end = e_off[g + 1];
    for (int base = beg; base < end; base += 128) {
        const int m = min(128, end - base);
        __syncthreads();
        if (t < m) {
            const int i = e_list[base + t];
            sp[t] = player_idx[i];
            sw[t] = v_reg_weight[i];
        }
        __syncthreads();
        #pragma unroll 4
        for (int j = 0; j < m; ++j) {
            const int   p = sp[j];
            const float w = sw[j];
            ushort4v x = *reinterpret_cast<const ushort4v*>(&ve_bf[(size_t)p * NH + c]);
            acc.x += w * bf2f(x.x); acc.y += w * bf2f(x.y);
            acc.z += w * bf2f(x.z); acc.w += w * bf2f(x.w);
        }
    }
    const float inv = 1.0f / e_reg_sum[g];
    acc.x *= inv; acc.y *= inv; acc.z *= inv; acc.w *= inv;
    __builtin_nontemporal_store(acc,
        reinterpret_cast<f32x4*>(&out_e[(size_t)g * NH + c]));
    uint2 pk;
    pk.x = pack2bf(acc.x, acc.y);
    pk.y = pack2bf(acc.z, acc.w);
    *reinterpret_cast<uint2*>(&Ebf[(size_t)g * NH + c]) = pk;    // cached: GEMM2 re-reads
}

// agg_v: v-term read from tiled+swizzled bf16 Abft (saves 51 MB f32-v read)
__global__ __launch_bounds__(128) void agg_v_bf16(
    const unsigned short* __restrict__ Abft, const float* __restrict__ v_weight,
    const unsigned short* __restrict__ ev_bf,
    const int* __restrict__ game_idx, const float* __restrict__ e_reg_weight,
    const int* __restrict__ v_off, const int* __restrict__ v_list,
    const float* __restrict__ v_reg_sum, float* __restrict__ out_v)
{
    __shared__ int   sg[128];
    __shared__ float sw[128];
    const int p = blockIdx.x;
    const int t = threadIdx.x;
    const int c = t << 2;
    const float vw = v_weight[p];
    // read bf16(v[p][c..c+3]) from the tiled+swizzled A buffer
    const size_t abase = ((size_t)(p >> 7) * 8 + (c >> 6)) * 16384;
    const int aphys = (((p & 127) * 128 + (c & 63) * 2)) ^ ((p & 7) << 4);
    ushort4v av = *reinterpret_cast<const ushort4v*>((const char*)Abft + abase + aphys);
    f32x4 acc;
    acc.x = bf2f(av.x) * vw; acc.y = bf2f(av.y) * vw;
    acc.z = bf2f(av.z) * vw; acc.w = bf2f(av.w) * vw;
    const int beg = v_off[p], end = v_off[p + 1];
    for (int base = beg; base < end; base += 128) {
        const int m = min(128, end - base);
        __syncthreads();
        if (t < m) {
            const int i = v_list[base + t];
            sg[t] = game_idx[i];
            sw[t] = e_reg_weight[i];
        }
        __syncthreads();
        #pragma unroll 4
        for (int j = 0; j < m; ++j) {
            const int   g = sg[j];
            const float w = sw[j];
            ushort4v x = *reinterpret_cast<const ushort4v*>(&ev_bf[(size_t)g * NH + c]);
            acc.x += w * bf2f(x.x); acc.y += w * bf2f(x.y);
            acc.z += w * bf2f(x.z); acc.w += w * bf2f(x.w);
        }
    }
    const float inv = 1.0f / v_reg_sum[p];
    acc.x *= inv; acc.y *= inv; acc.z *= inv; acc.w *= inv;
    __builtin_nontemporal_store(acc,
        reinterpret_cast<f32x4*>(&out_v[(size_t)p * NH + c]));
}

// ---------------- f32-gather aggregation (fallback) ----------------
__global__ __launch_bounds__(128) void agg_e_kernel(
    const float* __restrict__ e, const float* __restrict__ ve_w,
    const int* __restrict__ player_idx, const float* __restrict__ v_reg_weight,
    const int* __restrict__ e_off, const int* __restrict__ e_list,
    const float* __restrict__ e_reg_sum, float* __restrict__ out_e)
{
    __shared__ int   sp[128];
    __shared__ float sw[128];
    const int g = blockIdx.x;
    const int t = threadIdx.x;
    const int c = t << 2;
    float4 acc = *reinterpret_cast<const float4*>(&e[(size_t)g * NH + c]);
    const int beg = e_off[g], end = e_off[g + 1];
    for (int base = beg; base < end; base += 128) {
        const int m = min(128, end - base);
        __syncthreads();
        if (t < m) {
            const int i = e_list[base + t];
            sp[t] = player_idx[i];
            sw[t] = v_reg_weight[i];
        }
        __syncthreads();
        #pragma unroll 4
        for (int j = 0; j < m; ++j) {
            const int   p = sp[j];
            const float w = sw[j];
            float4 x = *reinterpret_cast<const float4*>(&ve_w[(size_t)p * NH + c]);
            acc.x += w * x.x; acc.y += w * x.y; acc.z += w * x.z; acc.w += w * x.w;
        }
    }
    const float inv = 1.0f / e_reg_sum[g];
    acc.x *= inv; acc.y *= inv; acc.z *= inv; acc.w *= inv;
    *reinterpret_cast<float4*>(&out_e[(size_t)g * NH + c]) = acc;
}

__global__ __launch_bounds__(128) void agg_v_kernel(
    const float* __restrict__ v, const float* __restrict__ v_weight,
    const float* __restrict__ ev_w,
    const int* __restrict__ game_idx, const float* __restrict__ e_reg_weight,
    const int* __restrict__ v_off, const int* __restrict__ v_list,
    const float* __restrict__ v_reg_sum, float* __restrict__ out_v)
{
    __shared__ int   sg[128];
    __shared__ float sw[128];
    const int p = blockIdx.x;
    const int t = threadIdx.x;
    const int c = t << 2;
    const float vw = v_weight[p];
    float4 acc = *reinterpret_cast<const float4*>(&v[(size_t)p * NH + c]);
    acc.x *= vw; acc.y *= vw; acc.z *= vw; acc.w *= vw;
    const int beg = v_off[p], end = v_off[p + 1];
    for (int base = beg; base < end; base += 128) {
        const int m = min(128, end - base);
        __syncthreads();
        if (t < m) {
            const int i = v_list[base + t];
            sg[t] = game_idx[i];
            sw[t] = e_reg_weight[i];
        }
        __syncthreads();
        #pragma unroll 4
        for (int j = 0; j < m; ++j) {
            const int   g = sg[j];
            const float w = sw[j];
            float4 x = *reinterpret_cast<const float4*>(&ev_w[(size_t)g * NH + c]);
            acc.x += w * x.x; acc.y += w * x.y; acc.z += w * x.z; acc.w += w * x.w;
        }
    }
    const float inv = 1.0f / v_reg_sum[p];
    acc.x *= inv; acc.y *= inv; acc.z *= inv; acc.w *= inv;
    *reinterpret_cast<float4*>(&out_v[(size_t)p * NH + c]) = acc;
}

// ---------------- atomic-path fallback kernels ----------------
__global__ __launch_bounds__(256) void scatter_add_kernel(
    const float* __restrict__ src, const int* __restrict__ gidx,
    const int* __restrict__ sidx, const float* __restrict__ regw,
    float* __restrict__ dst, int ni, int smin, int smax, int gmax)
{
    const int i = blockIdx.x * 2 + (threadIdx.x >> 7);
    if (i >= ni) return;
    const int s = sidx[i];
    if (s < smin || s >= smax) return;
    const int g = gidx[i];
    if (g < 0 || g >= gmax) return;
    const int c = (threadIdx.x & 127) << 2;
    const float w = regw[i];
    float4 val = *reinterpret_cast<const float4*>(&src[(size_t)g * NH + c]);
    float* d = &dst[(size_t)s * NH + c];
    atomicAdd(d + 0, val.x * w);
    atomicAdd(d + 1, val.y * w);
    atomicAdd(d + 2, val.z * w);
    atomicAdd(d + 3, val.w * w);
}

__global__ __launch_bounds__(256) void recompute_ev_scatter(
    const float* __restrict__ e_out, const float* __restrict__ W,
    const float* __restrict__ bias, const float* __restrict__ e_weight,
    const int* __restrict__ player_idx, const int* __restrict__ game_idx,
    const float* __restrict__ e_reg_weight, float* __restrict__ out_v, int pmin)
{
    const int i = blockIdx.x;
    const int p = player_idx[i];
    if (p < pmin || p >= NV) return;
    const int g = game_idx[i];
    if (g < 0 || g >= NE) return;
    __shared__ float eg[NH];
    const int t = threadIdx.x;
    eg[t]       = e_out[(size_t)g * NH + t];
    eg[t + 256] = e_out[(size_t)g * NH + t + 256];
    __syncthreads();
    float s0 = 0.f, s1 = 0.f;
    #pragma unroll 4
    for (int k = 0; k < NH; ++k) {
        const float ek = eg[k];
        s0 += ek * W[(size_t)k * NH + t];
        s1 += ek * W[(size_t)k * NH + t + 256];
    }
    const float ew = e_weight[g] * e_reg_weight[i];
    atomicAdd(&out_v[(size_t)p * NH + t],       fmaxf(s0 + bias[t], 0.f) * ew);
    atomicAdd(&out_v[(size_t)p * NH + t + 256], fmaxf(s1 + bias[t + 256], 0.f) * ew);
}

__global__ __launch_bounds__(256) void init_copy(
    const float* __restrict__ src, float* __restrict__ dst, int n4)
{
    const int i = blockIdx.x * 256 + threadIdx.x;
    if (i < n4)
        reinterpret_cast<float4*>(dst)[i] = reinterpret_cast<const float4*>(src)[i];
}

__global__ __launch_bounds__(256) void init_scale_rows(
    const float* __restrict__ src, const float* __restrict__ w,
    float* __restrict__ dst, int n4)
{
    const int i = blockIdx.x * 256 + threadIdx.x;
    if (i >= n4) return;
    const int row = i >> 7;
    const float s = w[row];
    float4 v = reinterpret_cast<const float4*>(src)[i];
    v.x *= s; v.y *= s; v.z *= s; v.w *= s;
    reinterpret_cast<float4*>(dst)[i] = v;
}

__global__ __launch_bounds__(256) void div_rows(
    const float* __restrict__ rs, float* __restrict__ x, int n4)
{
    const int i = blockIdx.x * 256 + threadIdx.x;
    if (i >= n4) return;
    const int row = i >> 7;
    const float inv = 1.0f / rs[row];
    float4 v = reinterpret_cast<float4*>(x)[i];
    v.x *= inv; v.y *= inv; v.z *= inv; v.w *= inv;
    reinterpret_cast<float4*>(x)[i] = v;
}

extern "C" void kernel_launch(void* const* d_in, const int* in_sizes, int n_in,
                              void* d_out, int out_size, void* d_ws, size_t ws_size,
                              hipStream_t stream) {
    const float* v            = (const float*)d_in[0];
    const float* e            = (const float*)d_in[1];
    const int*   player_idx   = (const int*)d_in[2];
    const int*   game_idx     = (const int*)d_in[3];
    const float* W_v2e        = (const float*)d_in[5];
    const float* W_e2v        = (const float*)d_in[6];
    const float* b_v          = (const float*)d_in[7];
    const float* b_e          = (const float*)d_in[8];

    const float* a9  = (const float*)d_in[9];
    const float* a10 = (const float*)d_in[10];
    const float* v_weight = (in_sizes[9]  == NV) ? a9  : a10;
    const float* e_weight = (in_sizes[9]  == NV) ? a10 : a9;
    const float* v_reg_weight = (const float*)d_in[11];
    const float* e_reg_weight = (const float*)d_in[12];
    const float* a13 = (const float*)d_in[13];
    const float* a14 = (const float*)d_in[14];
    const float* e_reg_sum = (in_sizes[13] == NE) ? a13 : a14;
    const float* v_reg_sum = (in_sizes[13] == NE) ? a14 : a13;

    float* out_v = (float*)d_out;
    float* out_e = (float*)d_out + (size_t)NV * NH;

    const dim3 blk(256);
    const int NB_E = (NE + 255) / 256;    // 40
    const int NB_V = (NV + 255) / 256;    // 196

    // ---- fast-path ws layout ----
    unsigned short* ev_bf = (unsigned short*)d_ws;            // [NE*NH]
    unsigned short* Ebf   = ev_bf + (size_t)NE * NH;          // [NE*NH] row-major
    int* e_cnt  = (int*)(Ebf + (size_t)NE * NH);
    int* v_cnt  = e_cnt + NE;
    int* e_cur  = v_cnt + NV;
    int* v_cur  = e_cur + NE;
    int* e_off  = v_cur + NV;
    int* v_off  = e_off + NE + 1;
    int* e_list = v_off + NV + 1;
    int* v_list = e_list + NI_TOT;
    int* e_bsum = v_list + NI_TOT;
    int* v_bsum = e_bsum + NB_E;
    unsigned short* Wt1t = (unsigned short*)(v_bsum + NB_V);  // tiled swz [4*8*8192]
    unsigned short* Wt2  = Wt1t + (size_t)4 * 8 * 8192;       // plain [NH*NH]
    unsigned short* Abft = Wt2 + (size_t)NH * NH;             // tiled swz [NT_A*8*8192]
    const size_t fast_need = (size_t)((char*)(Abft + (size_t)NT_A * 8 * 8192) - (char*)d_ws);

    if (ws_size >= fast_need && d_ws != nullptr) {
        // ---------- gld+swz GEMM1 / bf16 pipeline ----------
        transpose_cast_w_both<<<dim3(16, 16, 2), blk, 0, stream>>>(
            W_v2e, Wt1t, W_e2v, Wt2);
        const int ngroups = NT_A * 128 * 64;
        cast_tile_swz<<<(ngroups + 255) / 256, blk, 0, stream>>>(v, Abft, NV, ngroups);
        hipMemsetAsync(e_cnt, 0, sizeof(int) * 2 * (NE + NV), stream);
        hist_kernel<<<(NI_TOT + 255) / 256, blk, 0, stream>>>(
            game_idx, player_idx, e_cnt, v_cnt);
        scan_local_both<<<NB_E + NB_V, blk, 0, stream>>>(
            e_cnt, e_off, e_bsum, NE, NB_E, v_cnt, v_off, v_bsum, NV);
        scan_bsums_both<<<1, blk, 0, stream>>>(e_bsum, NB_E, v_bsum, NB_V);
        scan_add_both<<<NB_E + NB_V, blk, 0, stream>>>(
            e_off, e_bsum, NE, NB_E, v_off, v_bsum, NV);
        fill_kernel<<<(NI_TOT + 255) / 256, blk, 0, stream>>>(
            game_idx, player_idx, e_off, e_cur, e_list, v_off, v_cur, v_list);
        // GEMM1 -> ve_bf parked in out_v region (1D grid, XCD-swizzled)
        unsigned short* ve_bf = (unsigned short*)out_v;
        gemm_mfma_gld<<<dim3(NT_A * 4), blk, 0, stream>>>(
            Abft, Wt1t, b_v, v_weight, ve_bf, NV);
        agg_e_bf16<<<NE, dim3(128), 0, stream>>>(
            e, ve_bf, player_idx, v_reg_weight, e_off, e_list, e_reg_sum,
            out_e, Ebf);
        gemm_mfma_bf16a_bf16out<<<dim3(NH / 128, (NE + 127) / 128), blk, 0, stream>>>(
            Ebf, Wt2, b_e, e_weight, ev_bf, NE);
        agg_v_bf16<<<NV, dim3(128), 0, stream>>>(
            Abft, v_weight, ev_bf, game_idx, e_reg_weight, v_off, v_list,
            v_reg_sum, out_v);
        return;
    }

    // ---- fallback ws layout (f32 CSR path) ----
    float* ev_w = (float*)d_ws;
    int* f_e_cnt  = (int*)((char*)d_ws + (size_t)NE * NH * sizeof(float));
    int* f_v_cnt  = f_e_cnt + NE;
    int* f_e_cur  = f_v_cnt + NV;
    int* f_v_cur  = f_e_cur + NE;
    int* f_e_off  = f_v_cur + NV;
    int* f_v_off  = f_e_off + NE + 1;
    int* f_e_list = f_v_off + NV + 1;
    int* f_v_list = f_e_list + NI_TOT;
    const size_t csr_need = (size_t)((char*)(f_v_list + NI_TOT) - (char*)d_ws);

    if (ws_size >= csr_need && d_ws != nullptr) {
        gemm_relu_scale<<<dim3(NH / 64, (NV + 63) / 64), blk, 0, stream>>>(
            v, W_v2e, b_v, v_weight, out_v, NV);
        const int nz = 2 * (NE + NV);
        zero_ints<<<(nz + 255) / 256, blk, 0, stream>>>(f_e_cnt, nz);
        hist_kernel<<<(NI_TOT + 255) / 256, blk, 0, stream>>>(
            game_idx, player_idx, f_e_cnt, f_v_cnt);
        scan_kernel<<<1, blk, 0, stream>>>(f_e_cnt, f_e_off, NE);
        scan_kernel<<<1, blk, 0, stream>>>(f_v_cnt, f_v_off, NV);
        fill_kernel<<<(NI_TOT + 255) / 256, blk, 0, stream>>>(
            game_idx, player_idx, f_e_off, f_e_cur, f_e_list, f_v_off, f_v_cur, f_v_list);
        agg_e_kernel<<<NE, dim3(128), 0, stream>>>(
            e, out_v, player_idx, v_reg_weight, f_e_off, f_e_list, e_reg_sum, out_e);
        gemm_relu_scale<<<dim3(NH / 64, (NE + 63) / 64), blk, 0, stream>>>(
            out_e, W_e2v, b_e, e_weight, ev_w, NE);
        agg_v_kernel<<<NV, dim3(128), 0, stream>>>(
            v, v_weight, ev_w, game_idx, e_reg_weight, f_v_off, f_v_list,
            v_reg_sum, out_v);
        return;
    }

    // ---------- atomic fallback ----------
    const size_t evw_bytes = (size_t)NE * NH * sizeof(float);
    const bool big_ws = (ws_size >= evw_bytes) && (d_ws != nullptr);
    float* ev_w2 = big_ws ? (float*)d_ws : (out_v + (size_t)PB * NH);
    const int pb = big_ws ? NV : PB;
    const int n4_e = NE * NH / 4;

    gemm_relu_scale<<<dim3(NH / 64, (NV + 63) / 64), blk, 0, stream>>>(
        v, W_v2e, b_v, v_weight, out_v, NV);
    init_copy<<<(n4_e + 255) / 256, blk, 0, stream>>>(e, out_e, n4_e);
    scatter_add_kernel<<<(NI_TOT + 1) / 2, blk, 0, stream>>>(
        out_v, player_idx, game_idx, v_reg_weight, out_e, NI_TOT, 0, NE, NV);
    div_rows<<<(n4_e + 255) / 256, blk, 0, stream>>>(e_reg_sum, out_e, n4_e);
    gemm_relu_scale<<<dim3(NH / 64, (NE + 63) / 64), blk, 0, stream>>>(
        out_e, W_e2v, b_e, e_weight, ev_w2, NE);
    {
        const int n4 = pb * NH / 4;
        init_scale_rows<<<(n4 + 255) / 256, blk, 0, stream>>>(v, v_weight, out_v, n4);
    }
    scatter_add_kernel<<<(NI_TOT + 1) / 2, blk, 0, stream>>>(
        ev_w2, game_idx, player_idx, e_reg_weight, out_v, NI_TOT, 0, pb, NE);
    {
        const int n4 = pb * NH / 4;
        div_rows<<<(n4 + 255) / 256, blk, 0, stream>>>(v_reg_sum, out_v, n4);
    }
    if (!big_ws) {
        const int n4t = (NV - PB) * NH / 4;
        init_scale_rows<<<(n4t + 255) / 256, blk, 0, stream>>>(
            v + (size_t)PB * NH, v_weight + PB, out_v + (size_t)PB * NH, n4t);
        recompute_ev_scatter<<<NI_TOT, blk, 0, stream>>>(
            out_e, W_e2v, b_e, e_weight, player_idx, game_idx, e_reg_weight,
            out_v, PB);
        div_rows<<<(n4t + 255) / 256, blk, 0, stream>>>(
            v_reg_sum + PB, out_v + (size_t)PB * NH, n4t);
    }
}

// Round 17
// 302.789 us; speedup vs baseline: 1.2445x; 1.0151x over previous
//
#include <hip/hip_runtime.h>

#define NV 50000
#define NE 10000
#define NH 512
#define NI_TOT 300000
#define PB 40000
#define NT_A 391   // ceil(NV/128) row tiles for tiled A

typedef __attribute__((ext_vector_type(8))) short short8v;    // 8 bf16
typedef __attribute__((ext_vector_type(4))) float f32x4;
typedef __attribute__((ext_vector_type(4))) unsigned short ushort4v;

__device__ __forceinline__ unsigned short f2bf(float x) {
    union { float f; unsigned int u; } v; v.f = x;
    unsigned int r = (v.u + 0x7FFFu + ((v.u >> 16) & 1u)) >> 16;   // RNE
    return (unsigned short)r;
}
__device__ __forceinline__ unsigned int pack2bf(float lo, float hi) {
    return (unsigned int)f2bf(lo) | ((unsigned int)f2bf(hi) << 16);
}
__device__ __forceinline__ float bf2f(unsigned short u) {
    union { unsigned int x; float f; } v; v.x = ((unsigned int)u) << 16;
    return v.f;
}
__device__ __forceinline__ void gload16(const void* g, void* l) {
    __builtin_amdgcn_global_load_lds(
        (const __attribute__((address_space(1))) unsigned int*)g,
        (__attribute__((address_space(3))) unsigned int*)l, 16, 0, 0);
}

// ---------------- cast v -> tiled+swizzled bf16 A (zero-padded tail rows) -------
__global__ __launch_bounds__(256) void cast_tile_swz(
    const float* __restrict__ src, unsigned short* __restrict__ dst,
    int M, int ngroups)
{
    const int i = blockIdx.x * 256 + threadIdx.x;
    if (i >= ngroups) return;
    const int r  = i >> 6;
    const int gq = i & 63;
    uint4 o = make_uint4(0u, 0u, 0u, 0u);
    if (r < M) {
        const float4 a = *reinterpret_cast<const float4*>(&src[(size_t)r * NH + gq * 8]);
        const float4 b = *reinterpret_cast<const float4*>(&src[(size_t)r * NH + gq * 8 + 4]);
        o.x = pack2bf(a.x, a.y); o.y = pack2bf(a.z, a.w);
        o.z = pack2bf(b.x, b.y); o.w = pack2bf(b.z, b.w);
    }
    const size_t base = ((size_t)(r >> 7) * 8 + (gq >> 3)) * 16384;
    const int phys = (((r & 127) * 128 + (gq & 7) * 16)) ^ ((r & 7) << 4);
    *reinterpret_cast<uint4*>((char*)dst + base + phys) = o;
}

// ---------------- both W transposes in one launch (z: 0=tiled W1, 1=plain W2) ---
__global__ __launch_bounds__(256) void transpose_cast_w_both(
    const float* __restrict__ W1, unsigned short* __restrict__ Wt1t,
    const float* __restrict__ W2, unsigned short* __restrict__ Wt2)
{
    __shared__ float t[32][33];
    const int bx = blockIdx.x;          // n tile
    const int by = blockIdx.y;          // k tile
    const int tx = threadIdx.x & 31;
    const int ty = threadIdx.x >> 5;
    const float* W = (blockIdx.z == 0) ? W1 : W2;
    #pragma unroll
    for (int j = 0; j < 32; j += 8)
        t[ty + j][tx] = W[(size_t)(by * 32 + ty + j) * NH + bx * 32 + tx];
    __syncthreads();
    if (blockIdx.z == 0) {
        #pragma unroll
        for (int j = 0; j < 32; j += 8) {
            const int n = bx * 32 + ty + j;
            const int k = by * 32 + tx;
            const size_t base = ((size_t)(n >> 7) * 8 + (k >> 6)) * 16384;
            const int phys = (((n & 127) * 128 + (k & 63) * 2)) ^ ((n & 7) << 4);
            *reinterpret_cast<unsigned short*>((char*)Wt1t + base + phys) = f2bf(t[tx][ty + j]);
        }
    } else {
        #pragma unroll
        for (int j = 0; j < 32; j += 8)
            Wt2[(size_t)(bx * 32 + ty + j) * NH + by * 32 + tx] = f2bf(t[tx][ty + j]);
    }
}

// plain transpose (fallback paths)
__global__ __launch_bounds__(256) void transpose_cast_w(
    const float* __restrict__ W, unsigned short* __restrict__ Wt)
{
    __shared__ float t[32][33];
    const int bx = blockIdx.x;
    const int by = blockIdx.y;
    const int tx = threadIdx.x & 31;
    const int ty = threadIdx.x >> 5;
    #pragma unroll
    for (int j = 0; j < 32; j += 8)
        t[ty + j][tx] = W[(size_t)(by * 32 + ty + j) * NH + bx * 32 + tx];
    __syncthreads();
    #pragma unroll
    for (int j = 0; j < 32; j += 8)
        Wt[(size_t)(bx * 32 + ty + j) * NH + by * 32 + tx] = f2bf(t[tx][ty + j]);
}

// ---------------- GEMM1: dbuf global_load_lds + counted vmcnt (T4), bf16 out ----
__global__ __launch_bounds__(256) void gemm_mfma_gld(
    const unsigned short* __restrict__ At, const unsigned short* __restrict__ Btl,
    const float* __restrict__ bias, const float* __restrict__ rowscale,
    unsigned short* __restrict__ Cbf, int M)
{
    __shared__ __align__(16) unsigned char As[2][16384];
    __shared__ __align__(16) unsigned char Bs[2][16384];

    // bijective XCD remap: nwg = NT_A*4 = 8q+r
    const int nwg = NT_A * 4;
    const int bid = blockIdx.x;
    const int xcd = bid & 7;
    const int idx = bid >> 3;
    const int q = nwg >> 3, r = nwg & 7;
    const int wgid = (xcd < r ? xcd * (q + 1) : r * (q + 1) + (xcd - r) * q) + idx;
    const int rowt = wgid >> 2;
    const int colt = wgid & 3;

    const int tid  = threadIdx.x;
    const int lane = tid & 63;
    const int wave = tid >> 6;
    const int wm   = (wave & 1) * 64;
    const int wn   = (wave >> 1) * 64;
    const int tileM = rowt * 128;
    const int col0  = colt * 128;

    const char* Abase = (const char*)At  + (size_t)rowt * 8 * 16384;
    const char* Bbase = (const char*)Btl + (size_t)colt * 8 * 16384;

    // stage tile s into buffer buf (8 gload_lds per wave, zero VGPR data regs)
    auto STAGE = [&](int buf, int s) {
        const char* ga = Abase + s * 16384 + (size_t)wave * 4096 + lane * 16;
        const char* gb = Bbase + s * 16384 + (size_t)wave * 4096 + lane * 16;
        char* la = (char*)As[buf] + wave * 4096;
        char* lb = (char*)Bs[buf] + wave * 4096;
        #pragma unroll
        for (int i = 0; i < 4; ++i) {
            gload16(ga + i * 1024, la + i * 1024);
            gload16(gb + i * 1024, lb + i * 1024);
        }
    };

    f32x4 acc[4][4] = {};
    STAGE(0, 0);

    for (int s = 0; s < 8; ++s) {
        const int cur = s & 1;
        if (s < 7) {
            STAGE(cur ^ 1, s + 1);                       // next tile in flight
            asm volatile("s_waitcnt vmcnt(8)" ::: "memory");  // only tile-s loads done
        } else {
            asm volatile("s_waitcnt vmcnt(0)" ::: "memory");
        }
        __builtin_amdgcn_s_barrier();                    // raw: no vmcnt(0) drain
        __builtin_amdgcn_sched_barrier(0);

        #pragma unroll
        for (int ks = 0; ks < 2; ++ks) {
            const int kb = ks * 64 + (lane >> 4) * 16;
            short8v af[4], bfr[4];
            #pragma unroll
            for (int mf = 0; mf < 4; ++mf) {
                const int rr = wm + mf * 16 + (lane & 15);
                af[mf] = *reinterpret_cast<const short8v*>(
                    (const char*)As[cur] + ((rr * 128 + kb) ^ ((rr & 7) << 4)));
            }
            #pragma unroll
            for (int nf = 0; nf < 4; ++nf) {
                const int n = wn + nf * 16 + (lane & 15);
                bfr[nf] = *reinterpret_cast<const short8v*>(
                    (const char*)Bs[cur] + ((n * 128 + kb) ^ ((n & 7) << 4)));
            }
            #pragma unroll
            for (int mf = 0; mf < 4; ++mf)
                #pragma unroll
                for (int nf = 0; nf < 4; ++nf)
                    acc[mf][nf] = __builtin_amdgcn_mfma_f32_16x16x32_bf16(
                        af[mf], bfr[nf], acc[mf][nf], 0, 0, 0);
        }
        __builtin_amdgcn_s_barrier();                    // reads done before overwrite
    }

    const int rgrp = (lane >> 4) * 4;
    const int cin  = lane & 15;
    #pragma unroll
    for (int mf = 0; mf < 4; ++mf) {
        #pragma unroll
        for (int rr = 0; rr < 4; ++rr) {
            const int row = tileM + wm + mf * 16 + rgrp + rr;
            if (row < M) {
                const float rs = rowscale[row];
                #pragma unroll
                for (int nf = 0; nf < 4; ++nf) {
                    const int col = col0 + wn + nf * 16 + cin;
                    Cbf[(size_t)row * NH + col] =
                        f2bf(fmaxf(acc[mf][nf][rr] + bias[col], 0.f) * rs);
                }
            }
        }
    }
}

// ---------------- GEMM2: row-major bf16 A, plain Bt, reg staging ----------------
__global__ __launch_bounds__(256) void gemm_mfma_bf16a_bf16out(
    const unsigned short* __restrict__ Abf, const unsigned short* __restrict__ Bt,
    const float* __restrict__ bias, const float* __restrict__ rowscale,
    unsigned short* __restrict__ Cbf, int M)
{
    __shared__ unsigned short As[128][72];
    __shared__ unsigned short Bs[128][72];

    const int tid  = threadIdx.x;
    const int lane = tid & 63;
    const int wave = tid >> 6;
    const int wm   = (wave & 1) * 64;
    const int wn   = (wave >> 1) * 64;
    const int tileM = blockIdx.y * 128;
    const int col0  = blockIdx.x * 128;

    f32x4 acc[4][4] = {};
    const short8v zero8 = {0, 0, 0, 0, 0, 0, 0, 0};

    for (int k0 = 0; k0 < NH; k0 += 64) {
        #pragma unroll
        for (int j = 0; j < 4; ++j) {
            const int chunk = j * 256 + tid;
            const int n  = chunk >> 3;
            const int kc = (chunk & 7) * 8;
            const int arow = tileM + n;
            short8v a = zero8;
            if (arow < M)
                a = *reinterpret_cast<const short8v*>(&Abf[(size_t)arow * NH + k0 + kc]);
            *reinterpret_cast<short8v*>(&As[n][kc]) = a;
        }
        #pragma unroll
        for (int j = 0; j < 4; ++j) {
            const int chunk = j * 256 + tid;
            const int n  = chunk >> 3;
            const int kc = (chunk & 7) * 8;
            short8v b = *reinterpret_cast<const short8v*>(
                &Bt[(size_t)(col0 + n) * NH + k0 + kc]);
            *reinterpret_cast<short8v*>(&Bs[n][kc]) = b;
        }
        __syncthreads();

        #pragma unroll
        for (int ks = 0; ks < 2; ++ks) {
            const int koff = ks * 32 + (lane >> 4) * 8;
            short8v af[4], bfr[4];
            #pragma unroll
            for (int mf = 0; mf < 4; ++mf)
                af[mf] = *reinterpret_cast<short8v*>(&As[wm + mf * 16 + (lane & 15)][koff]);
            #pragma unroll
            for (int nf = 0; nf < 4; ++nf)
                bfr[nf] = *reinterpret_cast<short8v*>(&Bs[wn + nf * 16 + (lane & 15)][koff]);
            #pragma unroll
            for (int mf = 0; mf < 4; ++mf)
                #pragma unroll
                for (int nf = 0; nf < 4; ++nf)
                    acc[mf][nf] = __builtin_amdgcn_mfma_f32_16x16x32_bf16(
                        af[mf], bfr[nf], acc[mf][nf], 0, 0, 0);
        }
        __syncthreads();
    }

    const int rgrp = (lane >> 4) * 4;
    const int cin  = lane & 15;
    #pragma unroll
    for (int mf = 0; mf < 4; ++mf) {
        #pragma unroll
        for (int r = 0; r < 4; ++r) {
            const int row = tileM + wm + mf * 16 + rgrp + r;
            if (row < M) {
                const float rs = rowscale[row];
                #pragma unroll
                for (int nf = 0; nf < 4; ++nf) {
                    const int col = col0 + wn + nf * 16 + cin;
                    Cbf[(size_t)row * NH + col] =
                        f2bf(fmaxf(acc[mf][nf][r] + bias[col], 0.f) * rs);
                }
            }
        }
    }
}

// ---------------- f32 GEMM (fallback) ----------------
__global__ __launch_bounds__(256) void gemm_relu_scale(
    const float* __restrict__ A, const float* __restrict__ B,
    const float* __restrict__ bias, const float* __restrict__ rowscale,
    float* __restrict__ C, int M)
{
    __shared__ float As[16][68];
    __shared__ float Bs[16][64];
    const int tid = threadIdx.x;
    const int tx = tid & 15;
    const int ty = tid >> 4;
    const int tileM = blockIdx.y * 64;
    const int col0  = blockIdx.x * 64;
    const int lr  = tid >> 2;
    const int lk4 = (tid & 3) * 4;
    const int bc  = tid & 63;
    const int bk  = tid >> 6;
    float acc[4][4] = {};
    for (int k0 = 0; k0 < NH; k0 += 16) {
        const int arow = tileM + lr;
        float4 av = make_float4(0.f, 0.f, 0.f, 0.f);
        if (arow < M)
            av = *reinterpret_cast<const float4*>(&A[(size_t)arow * NH + k0 + lk4]);
        As[lk4 + 0][lr] = av.x; As[lk4 + 1][lr] = av.y;
        As[lk4 + 2][lr] = av.z; As[lk4 + 3][lr] = av.w;
        #pragma unroll
        for (int jj = 0; jj < 4; ++jj) {
            const int kk = bk + jj * 4;
            Bs[kk][bc] = B[(size_t)(k0 + kk) * NH + col0 + bc];
        }
        __syncthreads();
        #pragma unroll
        for (int kk = 0; kk < 16; ++kk) {
            float4 a = *reinterpret_cast<const float4*>(&As[kk][ty * 4]);
            float4 b = *reinterpret_cast<const float4*>(&Bs[kk][tx * 4]);
            acc[0][0] += a.x * b.x; acc[0][1] += a.x * b.y; acc[0][2] += a.x * b.z; acc[0][3] += a.x * b.w;
            acc[1][0] += a.y * b.x; acc[1][1] += a.y * b.y; acc[1][2] += a.y * b.z; acc[1][3] += a.y * b.w;
            acc[2][0] += a.z * b.x; acc[2][1] += a.z * b.y; acc[2][2] += a.z * b.z; acc[2][3] += a.z * b.w;
            acc[3][0] += a.w * b.x; acc[3][1] += a.w * b.y; acc[3][2] += a.w * b.z; acc[3][3] += a.w * b.w;
        }
        __syncthreads();
    }
    const int rbase = tileM + ty * 4;
    const int cbase = col0 + tx * 4;
    #pragma unroll
    for (int i = 0; i < 4; ++i) {
        const int row = rbase + i;
        if (row < M) {
            const float s = rowscale[row];
            float4 o;
            o.x = fmaxf(acc[i][0] + bias[cbase + 0], 0.f) * s;
            o.y = fmaxf(acc[i][1] + bias[cbase + 1], 0.f) * s;
            o.z = fmaxf(acc[i][2] + bias[cbase + 2], 0.f) * s;
            o.w = fmaxf(acc[i][3] + bias[cbase + 3], 0.f) * s;
            *reinterpret_cast<float4*>(&C[(size_t)row * NH + cbase]) = o;
        }
    }
}

// ---------------- CSR build ----------------
__global__ __launch_bounds__(256) void zero_ints(int* __restrict__ p, int n)
{
    const int i = blockIdx.x * 256 + threadIdx.x;
    if (i < n) p[i] = 0;
}

__global__ __launch_bounds__(256) void hist_kernel(
    const int* __restrict__ gi, const int* __restrict__ pi,
    int* __restrict__ e_cnt, int* __restrict__ v_cnt)
{
    const int i = blockIdx.x * 256 + threadIdx.x;
    if (i >= NI_TOT) return;
    atomicAdd(&e_cnt[gi[i]], 1);
    atomicAdd(&v_cnt[pi[i]], 1);
}

__device__ __forceinline__ void scan_local_body(
    const int* cnt, int* off, int* bsum, int n, int blk)
{
    __shared__ int buf[256];
    const int t = threadIdx.x;
    const int gi = blk * 256 + t;
    int x = (gi < n) ? cnt[gi] : 0;
    buf[t] = x;
    __syncthreads();
    #pragma unroll
    for (int d = 1; d < 256; d <<= 1) {
        int y = (t >= d) ? buf[t - d] : 0;
        __syncthreads();
        buf[t] += y;
        __syncthreads();
    }
    if (gi < n) off[gi + 1] = buf[t];
    if (t == 255) bsum[blk] = buf[255];
}

__global__ __launch_bounds__(256) void scan_local_both(
    const int* __restrict__ e_cnt, int* __restrict__ e_off, int* __restrict__ e_bsum, int ne, int nbe,
    const int* __restrict__ v_cnt, int* __restrict__ v_off, int* __restrict__ v_bsum, int nv)
{
    const int b = blockIdx.x;
    if (b < nbe) scan_local_body(e_cnt, e_off, e_bsum, ne, b);
    else         scan_local_body(v_cnt, v_off, v_bsum, nv, b - nbe);
}

__device__ __forceinline__ void scan_bsums_body(int* bsum, int nb)
{
    __shared__ int buf[256];
    const int t = threadIdx.x;
    const int x = (t < nb) ? bsum[t] : 0;
    buf[t] = x;
    __syncthreads();
    #pragma unroll
    for (int d = 1; d < 256; d <<= 1) {
        int y = (t >= d) ? buf[t - d] : 0;
        __syncthreads();
        buf[t] += y;
        __syncthreads();
    }
    if (t < nb) bsum[t] = buf[t] - x;
    __syncthreads();
}

__global__ __launch_bounds__(256) void scan_bsums_both(
    int* __restrict__ e_bsum, int nbe, int* __restrict__ v_bsum, int nbv)
{
    scan_bsums_body(e_bsum, nbe);
    scan_bsums_body(v_bsum, nbv);
}

__global__ __launch_bounds__(256) void scan_add_both(
    int* __restrict__ e_off, const int* __restrict__ e_bsum, int ne, int nbe,
    int* __restrict__ v_off, const int* __restrict__ v_bsum, int nv)
{
    const int b = blockIdx.x;
    const int t = threadIdx.x;
    if (b < nbe) {
        const int gi = b * 256 + t;
        if (gi == 0) e_off[0] = 0;
        if (gi < ne) e_off[gi + 1] += e_bsum[b];
    } else {
        const int gi = (b - nbe) * 256 + t;
        if (gi == 0) v_off[0] = 0;
        if (gi < nv) v_off[gi + 1] += v_bsum[b - nbe];
    }
}

__global__ __launch_bounds__(256) void scan_kernel(
    const int* __restrict__ cnt, int* __restrict__ off, int n)
{
    __shared__ int buf[256];
    __shared__ int carry_s;
    const int t = threadIdx.x;
    if (t == 0) { off[0] = 0; carry_s = 0; }
    __syncthreads();
    for (int base = 0; base < n; base += 256) {
        int x = (base + t < n) ? cnt[base + t] : 0;
        buf[t] = x;
        __syncthreads();
        #pragma unroll
        for (int d = 1; d < 256; d <<= 1) {
            int y = (t >= d) ? buf[t - d] : 0;
            __syncthreads();
            buf[t] += y;
            __syncthreads();
        }
        if (base + t < n) off[base + t + 1] = buf[t] + carry_s;
        __syncthreads();
        if (t == 255) carry_s += buf[255];
        __syncthreads();
    }
}

__global__ __launch_bounds__(256) void fill_kernel(
    const int* __restrict__ gi, const int* __restrict__ pi,
    const int* __restrict__ e_off, int* __restrict__ e_cur, int* __restrict__ e_list,
    const int* __restrict__ v_off, int* __restrict__ v_cur, int* __restrict__ v_list)
{
    const int i = blockIdx.x * 256 + threadIdx.x;
    if (i >= NI_TOT) return;
    const int g = gi[i];
    e_list[e_off[g] + atomicAdd(&e_cur[g], 1)] = i;
    const int p = pi[i];
    v_list[v_off[p] + atomicAdd(&v_cur[p], 1)] = i;
}

// ---------------- bf16-gather aggregation (NT streams) ----------------
__global__ __launch_bounds__(128) void agg_e_bf16(
    const float* __restrict__ e, const unsigned short* __restrict__ ve_bf,
    const int* __restrict__ player_idx, const float* __restrict__ v_reg_weight,
    const int* __restrict__ e_off, const int* __restrict__ e_list,
    const float* __restrict__ e_reg_sum, float* __restrict__ out_e,
    unsigned short* __restrict__ Ebf)
{
    __shared__ int   sp[128];
    __shared__ float sw[128];
    const int g = blockIdx.x;
    const int t = threadIdx.x;
    const int c = t << 2;
    f32x4 acc = __builtin_nontemporal_load(
        reinterpret_cast<const f32x4*>(&e[(size_t)g * NH + c]));
    const int beg = e_off[g], end = e_off[g + 1];
    for (int base = beg; base < end; base += 128) {
        const int m = min(128, end - base);
        __syncthreads();
        if (t < m) {
            const int i = e_list[base + t];
            sp[t] = player_idx[i];
            sw[t] = v_reg_weight[i];
        }
        __syncthreads();
        #pragma unroll 4
        for (int j = 0; j < m; ++j) {
            const int   p = sp[j];
            const float w = sw[j];
            ushort4v x = *reinterpret_cast<const ushort4v*>(&ve_bf[(size_t)p * NH + c]);
            acc.x += w * bf2f(x.x); acc.y += w * bf2f(x.y);
            acc.z += w * bf2f(x.z); acc.w += w * bf2f(x.w);
        }
    }
    const float inv = 1.0f / e_reg_sum[g];
    acc.x *= inv; acc.y *= inv; acc.z *= inv; acc.w *= inv;
    __builtin_nontemporal_store(acc,
        reinterpret_cast<f32x4*>(&out_e[(size_t)g * NH + c]));
    uint2 pk;
    pk.x = pack2bf(acc.x, acc.y);
    pk.y = pack2bf(acc.z, acc.w);
    *reinterpret_cast<uint2*>(&Ebf[(size_t)g * NH + c]) = pk;    // cached: GEMM2 re-reads
}

// agg_v: round-15 form (f32 NT v-term; Abft variant was measured neutral/negative)
__global__ __launch_bounds__(128) void agg_v_bf16(
    const float* __restrict__ v, const float* __restrict__ v_weight,
    const unsigned short* __restrict__ ev_bf,
    const int* __restrict__ game_idx, const float* __restrict__ e_reg_weight,
    const int* __restrict__ v_off, const int* __restrict__ v_list,
    const float* __restrict__ v_reg_sum, float* __restrict__ out_v)
{
    __shared__ int   sg[128];
    __shared__ float sw[128];
    const int p = blockIdx.x;
    const int t = threadIdx.x;
    const int c = t << 2;
    const float vw = v_weight[p];
    f32x4 acc = __builtin_nontemporal_load(
        reinterpret_cast<const f32x4*>(&v[(size_t)p * NH + c]));
    acc.x *= vw; acc.y *= vw; acc.z *= vw; acc.w *= vw;
    const int beg = v_off[p], end = v_off[p + 1];
    for (int base = beg; base < end; base += 128) {
        const int m = min(128, end - base);
        __syncthreads();
        if (t < m) {
            const int i = v_list[base + t];
            sg[t] = game_idx[i];
            sw[t] = e_reg_weight[i];
        }
        __syncthreads();
        #pragma unroll 4
        for (int j = 0; j < m; ++j) {
            const int   g = sg[j];
            const float w = sw[j];
            ushort4v x = *reinterpret_cast<const ushort4v*>(&ev_bf[(size_t)g * NH + c]);
            acc.x += w * bf2f(x.x); acc.y += w * bf2f(x.y);
            acc.z += w * bf2f(x.z); acc.w += w * bf2f(x.w);
        }
    }
    const float inv = 1.0f / v_reg_sum[p];
    acc.x *= inv; acc.y *= inv; acc.z *= inv; acc.w *= inv;
    __builtin_nontemporal_store(acc,
        reinterpret_cast<f32x4*>(&out_v[(size_t)p * NH + c]));
}

// ---------------- f32-gather aggregation (fallback) ----------------
__global__ __launch_bounds__(128) void agg_e_kernel(
    const float* __restrict__ e, const float* __restrict__ ve_w,
    const int* __restrict__ player_idx, const float* __restrict__ v_reg_weight,
    const int* __restrict__ e_off, const int* __restrict__ e_list,
    const float* __restrict__ e_reg_sum, float* __restrict__ out_e)
{
    __shared__ int   sp[128];
    __shared__ float sw[128];
    const int g = blockIdx.x;
    const int t = threadIdx.x;
    const int c = t << 2;
    float4 acc = *reinterpret_cast<const float4*>(&e[(size_t)g * NH + c]);
    const int beg = e_off[g], end = e_off[g + 1];
    for (int base = beg; base < end; base += 128) {
        const int m = min(128, end - base);
        __syncthreads();
        if (t < m) {
            const int i = e_list[base + t];
            sp[t] = player_idx[i];
            sw[t] = v_reg_weight[i];
        }
        __syncthreads();
        #pragma unroll 4
        for (int j = 0; j < m; ++j) {
            const int   p = sp[j];
            const float w = sw[j];
            float4 x = *reinterpret_cast<const float4*>(&ve_w[(size_t)p * NH + c]);
            acc.x += w * x.x; acc.y += w * x.y; acc.z += w * x.z; acc.w += w * x.w;
        }
    }
    const float inv = 1.0f / e_reg_sum[g];
    acc.x *= inv; acc.y *= inv; acc.z *= inv; acc.w *= inv;
    *reinterpret_cast<float4*>(&out_e[(size_t)g * NH + c]) = acc;
}

__global__ __launch_bounds__(128) void agg_v_kernel(
    const float* __restrict__ v, const float* __restrict__ v_weight,
    const float* __restrict__ ev_w,
    const int* __restrict__ game_idx, const float* __restrict__ e_reg_weight,
    const int* __restrict__ v_off, const int* __restrict__ v_list,
    const float* __restrict__ v_reg_sum, float* __restrict__ out_v)
{
    __shared__ int   sg[128];
    __shared__ float sw[128];
    const int p = blockIdx.x;
    const int t = threadIdx.x;
    const int c = t << 2;
    const float vw = v_weight[p];
    float4 acc = *reinterpret_cast<const float4*>(&v[(size_t)p * NH + c]);
    acc.x *= vw; acc.y *= vw; acc.z *= vw; acc.w *= vw;
    const int beg = v_off[p], end = v_off[p + 1];
    for (int base = beg; base < end; base += 128) {
        const int m = min(128, end - base);
        __syncthreads();
        if (t < m) {
            const int i = v_list[base + t];
            sg[t] = game_idx[i];
            sw[t] = e_reg_weight[i];
        }
        __syncthreads();
        #pragma unroll 4
        for (int j = 0; j < m; ++j) {
            const int   g = sg[j];
            const float w = sw[j];
            float4 x = *reinterpret_cast<const float4*>(&ev_w[(size_t)g * NH + c]);
            acc.x += w * x.x; acc.y += w * x.y; acc.z += w * x.z; acc.w += w * x.w;
        }
    }
    const float inv = 1.0f / v_reg_sum[p];
    acc.x *= inv; acc.y *= inv; acc.z *= inv; acc.w *= inv;
    *reinterpret_cast<float4*>(&out_v[(size_t)p * NH + c]) = acc;
}

// ---------------- atomic-path fallback kernels ----------------
__global__ __launch_bounds__(256) void scatter_add_kernel(
    const float* __restrict__ src, const int* __restrict__ gidx,
    const int* __restrict__ sidx, const float* __restrict__ regw,
    float* __restrict__ dst, int ni, int smin, int smax, int gmax)
{
    const int i = blockIdx.x * 2 + (threadIdx.x >> 7);
    if (i >= ni) return;
    const int s = sidx[i];
    if (s < smin || s >= smax) return;
    const int g = gidx[i];
    if (g < 0 || g >= gmax) return;
    const int c = (threadIdx.x & 127) << 2;
    const float w = regw[i];
    float4 val = *reinterpret_cast<const float4*>(&src[(size_t)g * NH + c]);
    float* d = &dst[(size_t)s * NH + c];
    atomicAdd(d + 0, val.x * w);
    atomicAdd(d + 1, val.y * w);
    atomicAdd(d + 2, val.z * w);
    atomicAdd(d + 3, val.w * w);
}

__global__ __launch_bounds__(256) void recompute_ev_scatter(
    const float* __restrict__ e_out, const float* __restrict__ W,
    const float* __restrict__ bias, const float* __restrict__ e_weight,
    const int* __restrict__ player_idx, const int* __restrict__ game_idx,
    const float* __restrict__ e_reg_weight, float* __restrict__ out_v, int pmin)
{
    const int i = blockIdx.x;
    const int p = player_idx[i];
    if (p < pmin || p >= NV) return;
    const int g = game_idx[i];
    if (g < 0 || g >= NE) return;
    __shared__ float eg[NH];
    const int t = threadIdx.x;
    eg[t]       = e_out[(size_t)g * NH + t];
    eg[t + 256] = e_out[(size_t)g * NH + t + 256];
    __syncthreads();
    float s0 = 0.f, s1 = 0.f;
    #pragma unroll 4
    for (int k = 0; k < NH; ++k) {
        const float ek = eg[k];
        s0 += ek * W[(size_t)k * NH + t];
        s1 += ek * W[(size_t)k * NH + t + 256];
    }
    const float ew = e_weight[g] * e_reg_weight[i];
    atomicAdd(&out_v[(size_t)p * NH + t],       fmaxf(s0 + bias[t], 0.f) * ew);
    atomicAdd(&out_v[(size_t)p * NH + t + 256], fmaxf(s1 + bias[t + 256], 0.f) * ew);
}

__global__ __launch_bounds__(256) void init_copy(
    const float* __restrict__ src, float* __restrict__ dst, int n4)
{
    const int i = blockIdx.x * 256 + threadIdx.x;
    if (i < n4)
        reinterpret_cast<float4*>(dst)[i] = reinterpret_cast<const float4*>(src)[i];
}

__global__ __launch_bounds__(256) void init_scale_rows(
    const float* __restrict__ src, const float* __restrict__ w,
    float* __restrict__ dst, int n4)
{
    const int i = blockIdx.x * 256 + threadIdx.x;
    if (i >= n4) return;
    const int row = i >> 7;
    const float s = w[row];
    float4 v = reinterpret_cast<const float4*>(src)[i];
    v.x *= s; v.y *= s; v.z *= s; v.w *= s;
    reinterpret_cast<float4*>(dst)[i] = v;
}

__global__ __launch_bounds__(256) void div_rows(
    const float* __restrict__ rs, float* __restrict__ x, int n4)
{
    const int i = blockIdx.x * 256 + threadIdx.x;
    if (i >= n4) return;
    const int row = i >> 7;
    const float inv = 1.0f / rs[row];
    float4 v = reinterpret_cast<float4*>(x)[i];
    v.x *= inv; v.y *= inv; v.z *= inv; v.w *= inv;
    reinterpret_cast<float4*>(x)[i] = v;
}

extern "C" void kernel_launch(void* const* d_in, const int* in_sizes, int n_in,
                              void* d_out, int out_size, void* d_ws, size_t ws_size,
                              hipStream_t stream) {
    const float* v            = (const float*)d_in[0];
    const float* e            = (const float*)d_in[1];
    const int*   player_idx   = (const int*)d_in[2];
    const int*   game_idx     = (const int*)d_in[3];
    const float* W_v2e        = (const float*)d_in[5];
    const float* W_e2v        = (const float*)d_in[6];
    const float* b_v          = (const float*)d_in[7];
    const float* b_e          = (const float*)d_in[8];

    const float* a9  = (const float*)d_in[9];
    const float* a10 = (const float*)d_in[10];
    const float* v_weight = (in_sizes[9]  == NV) ? a9  : a10;
    const float* e_weight = (in_sizes[9]  == NV) ? a10 : a9;
    const float* v_reg_weight = (const float*)d_in[11];
    const float* e_reg_weight = (const float*)d_in[12];
    const float* a13 = (const float*)d_in[13];
    const float* a14 = (const float*)d_in[14];
    const float* e_reg_sum = (in_sizes[13] == NE) ? a13 : a14;
    const float* v_reg_sum = (in_sizes[13] == NE) ? a14 : a13;

    float* out_v = (float*)d_out;
    float* out_e = (float*)d_out + (size_t)NV * NH;

    const dim3 blk(256);
    const int NB_E = (NE + 255) / 256;    // 40
    const int NB_V = (NV + 255) / 256;    // 196

    // ---- fast-path ws layout ----
    unsigned short* ev_bf = (unsigned short*)d_ws;            // [NE*NH]
    unsigned short* Ebf   = ev_bf + (size_t)NE * NH;          // [NE*NH] row-major
    int* e_cnt  = (int*)(Ebf + (size_t)NE * NH);
    int* v_cnt  = e_cnt + NE;
    int* e_cur  = v_cnt + NV;
    int* v_cur  = e_cur + NE;
    int* e_off  = v_cur + NV;
    int* v_off  = e_off + NE + 1;
    int* e_list = v_off + NV + 1;
    int* v_list = e_list + NI_TOT;
    int* e_bsum = v_list + NI_TOT;
    int* v_bsum = e_bsum + NB_E;
    unsigned short* Wt1t = (unsigned short*)(v_bsum + NB_V);  // tiled swz [4*8*8192]
    unsigned short* Wt2  = Wt1t + (size_t)4 * 8 * 8192;       // plain [NH*NH]
    unsigned short* Abft = Wt2 + (size_t)NH * NH;             // tiled swz [NT_A*8*8192]
    const size_t fast_need = (size_t)((char*)(Abft + (size_t)NT_A * 8 * 8192) - (char*)d_ws);

    if (ws_size >= fast_need && d_ws != nullptr) {
        // ---------- gld+swz GEMM1 / bf16 pipeline ----------
        transpose_cast_w_both<<<dim3(16, 16, 2), blk, 0, stream>>>(
            W_v2e, Wt1t, W_e2v, Wt2);
        const int ngroups = NT_A * 128 * 64;
        cast_tile_swz<<<(ngroups + 255) / 256, blk, 0, stream>>>(v, Abft, NV, ngroups);
        hipMemsetAsync(e_cnt, 0, sizeof(int) * 2 * (NE + NV), stream);
        hist_kernel<<<(NI_TOT + 255) / 256, blk, 0, stream>>>(
            game_idx, player_idx, e_cnt, v_cnt);
        scan_local_both<<<NB_E + NB_V, blk, 0, stream>>>(
            e_cnt, e_off, e_bsum, NE, NB_E, v_cnt, v_off, v_bsum, NV);
        scan_bsums_both<<<1, blk, 0, stream>>>(e_bsum, NB_E, v_bsum, NB_V);
        scan_add_both<<<NB_E + NB_V, blk, 0, stream>>>(
            e_off, e_bsum, NE, NB_E, v_off, v_bsum, NV);
        fill_kernel<<<(NI_TOT + 255) / 256, blk, 0, stream>>>(
            game_idx, player_idx, e_off, e_cur, e_list, v_off, v_cur, v_list);
        // GEMM1 -> ve_bf parked in out_v region (1D grid, XCD-swizzled, T4 dbuf)
        unsigned short* ve_bf = (unsigned short*)out_v;
        gemm_mfma_gld<<<dim3(NT_A * 4), blk, 0, stream>>>(
            Abft, Wt1t, b_v, v_weight, ve_bf, NV);
        agg_e_bf16<<<NE, dim3(128), 0, stream>>>(
            e, ve_bf, player_idx, v_reg_weight, e_off, e_list, e_reg_sum,
            out_e, Ebf);
        gemm_mfma_bf16a_bf16out<<<dim3(NH / 128, (NE + 127) / 128), blk, 0, stream>>>(
            Ebf, Wt2, b_e, e_weight, ev_bf, NE);
        agg_v_bf16<<<NV, dim3(128), 0, stream>>>(
            v, v_weight, ev_bf, game_idx, e_reg_weight, v_off, v_list,
            v_reg_sum, out_v);
        return;
    }

    // ---- fallback ws layout (f32 CSR path) ----
    float* ev_w = (float*)d_ws;
    int* f_e_cnt  = (int*)((char*)d_ws + (size_t)NE * NH * sizeof(float));
    int* f_v_cnt  = f_e_cnt + NE;
    int* f_e_cur  = f_v_cnt + NV;
    int* f_v_cur  = f_e_cur + NE;
    int* f_e_off  = f_v_cur + NV;
    int* f_v_off  = f_e_off + NE + 1;
    int* f_e_list = f_v_off + NV + 1;
    int* f_v_list = f_e_list + NI_TOT;
    const size_t csr_need = (size_t)((char*)(f_v_list + NI_TOT) - (char*)d_ws);

    if (ws_size >= csr_need && d_ws != nullptr) {
        gemm_relu_scale<<<dim3(NH / 64, (NV + 63) / 64), blk, 0, stream>>>(
            v, W_v2e, b_v, v_weight, out_v, NV);
        const int nz = 2 * (NE + NV);
        zero_ints<<<(nz + 255) / 256, blk, 0, stream>>>(f_e_cnt, nz);
        hist_kernel<<<(NI_TOT + 255) / 256, blk, 0, stream>>>(
            game_idx, player_idx, f_e_cnt, f_v_cnt);
        scan_kernel<<<1, blk, 0, stream>>>(f_e_cnt, f_e_off, NE);
        scan_kernel<<<1, blk, 0, stream>>>(f_v_cnt, f_v_off, NV);
        fill_kernel<<<(NI_TOT + 255) / 256, blk, 0, stream>>>(
            game_idx, player_idx, f_e_off, f_e_cur, f_e_list, f_v_off, f_v_cur, f_v_list);
        agg_e_kernel<<<NE, dim3(128), 0, stream>>>(
            e, out_v, player_idx, v_reg_weight, f_e_off, f_e_list, e_reg_sum, out_e);
        gemm_relu_scale<<<dim3(NH / 64, (NE + 63) / 64), blk, 0, stream>>>(
            out_e, W_e2v, b_e, e_weight, ev_w, NE);
        agg_v_kernel<<<NV, dim3(128), 0, stream>>>(
            v, v_weight, ev_w, game_idx, e_reg_weight, f_v_off, f_v_list,
            v_reg_sum, out_v);
        return;
    }

    // ---------- atomic fallback ----------
    const size_t evw_bytes = (size_t)NE * NH * sizeof(float);
    const bool big_ws = (ws_size >= evw_bytes) && (d_ws != nullptr);
    float* ev_w2 = big_ws ? (float*)d_ws : (out_v + (size_t)PB * NH);
    const int pb = big_ws ? NV : PB;
    const int n4_e = NE * NH / 4;

    gemm_relu_scale<<<dim3(NH / 64, (NV + 63) / 64), blk, 0, stream>>>(
        v, W_v2e, b_v, v_weight, out_v, NV);
    init_copy<<<(n4_e + 255) / 256, blk, 0, stream>>>(e, out_e, n4_e);
    scatter_add_kernel<<<(NI_TOT + 1) / 2, blk, 0, stream>>>(
        out_v, player_idx, game_idx, v_reg_weight, out_e, NI_TOT, 0, NE, NV);
    div_rows<<<(n4_e + 255) / 256, blk, 0, stream>>>(e_reg_sum, out_e, n4_e);
    gemm_relu_scale<<<dim3(NH / 64, (NE + 63) / 64), blk, 0, stream>>>(
        out_e, W_e2v, b_e, e_weight, ev_w2, NE);
    {
        const int n4 = pb * NH / 4;
        init_scale_rows<<<(n4 + 255) / 256, blk, 0, stream>>>(v, v_weight, out_v, n4);
    }
    scatter_add_kernel<<<(NI_TOT + 1) / 2, blk, 0, stream>>>(
        ev_w2, game_idx, player_idx, e_reg_weight, out_v, NI_TOT, 0, pb, NE);
    {
        const int n4 = pb * NH / 4;
        div_rows<<<(n4 + 255) / 256, blk, 0, stream>>>(v_reg_sum, out_v, n4);
    }
    if (!big_ws) {
        const int n4t = (NV - PB) * NH / 4;
        init_scale_rows<<<(n4t + 255) / 256, blk, 0, stream>>>(
            v + (size_t)PB * NH, v_weight + PB, out_v + (size_t)PB * NH, n4t);
        recompute_ev_scatter<<<NI_TOT, blk, 0, stream>>>(
            out_e, W_e2v, b_e, e_weight, player_idx, game_idx, e_reg_weight,
            out_v, PB);
        div_rows<<<(n4t + 255) / 256, blk, 0, stream>>>(
            v_reg_sum + PB, out_v + (size_t)PB * NH, n4t);
    }
}